// Round 4
// baseline (406.533 us; speedup 1.0000x reference)
//
#include <hip/hip_runtime.h>
#include <hip/hip_bf16.h>
#include <stdint.h>

// Problem: B=1, S=4096, HIDDEN=2048, HEADS=16, HEAD_DIM=128, causal MHA.
// All inputs fp32; output fp32. Compute in bf16 MFMA with fp32 accum.
//
// Workspace layout (bytes), total ~112 MB:
//   xb   [4096][2048] bf16 @ 0          (16 MB)
//   WqT  [2048][2048] bf16 @ 16 MB      (8 MB)   (transposed: [out][in])
//   WkT  @ 24 MB, WvT @ 32 MB, WoT @ 40 MB
//   Qb   [4096][2048] bf16 @ 48 MB
//   Kb   [4096][2048] bf16 @ 64 MB
//   VTb  [2048][4096] bf16 @ 80 MB      (V transposed per-head: row h*128+d, col s)
//   Ctx  [4096][2048] bf16 @ 96 MB

#define SQ 4096
#define HID 2048
#define NH 16
#define HD 128

typedef __attribute__((ext_vector_type(8))) short bf16x8;
typedef __attribute__((ext_vector_type(4))) float f32x4;
typedef __attribute__((ext_vector_type(4))) unsigned short us4;

__device__ inline unsigned short f2bf(float f) {
    unsigned int u = __builtin_bit_cast(unsigned int, f);
    u = (u + 0x7FFFu + ((u >> 16) & 1u)) >> 16;
    return (unsigned short)u;
}

__device__ inline void gl2lds16(const void* g, void* l) {
    __builtin_amdgcn_global_load_lds(
        (const __attribute__((address_space(1))) unsigned int*)g,
        (__attribute__((address_space(3))) unsigned int*)l, 16, 0, 0);
}

// ---------------- fp32 -> bf16 convert (grid-stride, float4) ----------------
__global__ void cvt_f32_bf16(const float* __restrict__ src,
                             unsigned short* __restrict__ dst, int n) {
    int i = (blockIdx.x * blockDim.x + threadIdx.x) * 4;
    int stride = gridDim.x * blockDim.x * 4;
    for (; i < n; i += stride) {
        float4 v = *(const float4*)(src + i);
        us4 o;
        o.x = f2bf(v.x); o.y = f2bf(v.y); o.z = f2bf(v.z); o.w = f2bf(v.w);
        *(us4*)(dst + i) = o;
    }
}

// -------- transpose + convert: W [K][N] f32 -> WT [N][K] bf16 (2048x2048) ---
__global__ void transcvt(const float* __restrict__ W, unsigned short* __restrict__ WT) {
    __shared__ float tile[64][65];
    int n0 = blockIdx.x * 64, k0 = blockIdx.y * 64;
    int t = threadIdx.x;
    for (int i = 0; i < 4; i++) {
        int idx = i * 256 + t;          // 0..1023
        int k = idx >> 4;               // 64 rows, 16 float4 per row
        int n4 = (idx & 15) << 2;
        float4 v = *(const float4*)(W + (size_t)(k0 + k) * HID + n0 + n4);
        tile[k][n4 + 0] = v.x; tile[k][n4 + 1] = v.y;
        tile[k][n4 + 2] = v.z; tile[k][n4 + 3] = v.w;
    }
    __syncthreads();
    for (int i = 0; i < 4; i++) {
        int idx = i * 256 + t;
        int n = idx >> 4;
        int k4 = (idx & 15) << 2;
        us4 o;
        o.x = f2bf(tile[k4 + 0][n]); o.y = f2bf(tile[k4 + 1][n]);
        o.z = f2bf(tile[k4 + 2][n]); o.w = f2bf(tile[k4 + 3][n]);
        *(us4*)(WT + (size_t)(n0 + n) * HID + k0 + k4) = o;
    }
}

// ---------------- bf16 GEMM: C[M,N] = A[M,K] @ BT[N,K]^T (+bias) ------------
// M=4096, N=2048, K=2048. 128x128 tile, BK=64, 256 thr = 4 waves (2x2 of 64x64).
// OUTMODE 0: bf16 out [M][N] + bias; 1: bf16 out transposed [N][M] + bias;
//         2: f32 out [M][N], no bias.
template <int OUTMODE>
__global__ __launch_bounds__(256) void gemm_bf16(
    const unsigned short* __restrict__ A, const unsigned short* __restrict__ BT,
    const float* __restrict__ bias, void* __restrict__ C) {
    const int M = 4096, N = 2048, K = 2048;
    __shared__ __align__(16) unsigned short As[128 * 64];
    __shared__ __align__(16) unsigned short Bs[128 * 64];
    int m0 = blockIdx.x * 128, n0 = blockIdx.y * 128;
    int t = threadIdx.x;
    int lane = t & 63, wid = t >> 6;
    int wm = wid >> 1, wn = wid & 1;
    f32x4 acc[4][4] = {};

    for (int k0 = 0; k0 < K; k0 += 64) {
        for (int i = 0; i < 4; i++) {
            int idx = i * 256 + t;           // 1024 x 16B loads per tile
            int r = idx >> 3;                // row 0..127 (8 loads of 8 elems per row)
            int c = (idx & 7) << 3;
            void* ldsA = (void*)(As + ((i * 256 + wid * 64) << 3));
            void* ldsB = (void*)(Bs + ((i * 256 + wid * 64) << 3));
            gl2lds16(A + (size_t)(m0 + r) * K + k0 + c, ldsA);
            gl2lds16(BT + (size_t)(n0 + r) * K + k0 + c, ldsB);
        }
        __syncthreads();
        for (int kk = 0; kk < 2; kk++) {
            int ko = kk * 32 + ((lane >> 4) << 3);
            bf16x8 af[4], bfg[4];
            for (int mf = 0; mf < 4; mf++)
                af[mf] = *(const bf16x8*)(As + (wm * 64 + mf * 16 + (lane & 15)) * 64 + ko);
            for (int nf = 0; nf < 4; nf++)
                bfg[nf] = *(const bf16x8*)(Bs + (wn * 64 + nf * 16 + (lane & 15)) * 64 + ko);
            for (int mf = 0; mf < 4; mf++)
                for (int nf = 0; nf < 4; nf++)
                    acc[mf][nf] = __builtin_amdgcn_mfma_f32_16x16x32_bf16(
                        af[mf], bfg[nf], acc[mf][nf], 0, 0, 0);
        }
        __syncthreads();
    }

    int rbase = (lane >> 4) << 2;
    for (int mf = 0; mf < 4; mf++) {
        for (int nf = 0; nf < 4; nf++) {
            int n_g = n0 + wn * 64 + nf * 16 + (lane & 15);
            int m_base = m0 + wm * 64 + mf * 16 + rbase;
            float b = (OUTMODE == 2) ? 0.f : bias[n_g];
            if (OUTMODE == 0) {
                unsigned short* Cb = (unsigned short*)C;
                for (int r = 0; r < 4; r++)
                    Cb[(size_t)(m_base + r) * N + n_g] = f2bf(acc[mf][nf][r] + b);
            } else if (OUTMODE == 1) {
                unsigned short* Cb = (unsigned short*)C;
                us4 o;
                o.x = f2bf(acc[mf][nf][0] + b); o.y = f2bf(acc[mf][nf][1] + b);
                o.z = f2bf(acc[mf][nf][2] + b); o.w = f2bf(acc[mf][nf][3] + b);
                *(us4*)(Cb + (size_t)n_g * M + m_base) = o;
            } else {
                float* Cf = (float*)C;
                for (int r = 0; r < 4; r++)
                    Cf[(size_t)(m_base + r) * N + n_g] = acc[mf][nf][r];
            }
        }
    }
}

// ---------------- causal flash attention (v4) --------------------------------
// grid (NH, 32); 256 thr = 4 waves; QBLK=64 (wave w owns rows qbase+w*16..+15).
// Block (h, bx) processes q-strips bx and 63-bx -> exactly 65 KV-tiles/block:
// perfect balance. 512 blocks, 72 KB LDS -> 2 blocks/CU (cross-block overlap
// hides staging+barrier drains). head on blockIdx.x => blocks of heads {h,h+8}
// land on XCD h%8 (id%8 heuristic) and share KV tiles through that L2.
// K/V double-buffered + prefetch; XOR-swizzled LDS (pre-swizzled global src).
__global__ __launch_bounds__(256) void attn(
    const unsigned short* __restrict__ Q, const unsigned short* __restrict__ Kc,
    const unsigned short* __restrict__ VT, unsigned short* __restrict__ O) {
    __shared__ __align__(16) unsigned short Kb[2][64 * 128];
    __shared__ __align__(16) unsigned short Vb[2][128 * 64];
    __shared__ __align__(16) unsigned short Pt[4][16 * 64];
    int h = blockIdx.x;
    int bx = blockIdx.y;
    int t = threadIdx.x, lane = t & 63, w = t >> 6;
    int lr = lane & 15, hi = lane >> 4;
    const float scale = 0.08838834764831845f;  // 1/sqrt(128)

    // stage K/V tile kv0 into buffer `buf`, swizzled source (linear LDS dest).
    auto stage = [&](int buf, int kv0) {
        for (int i = 0; i < 4; i++) {
            int idx = i * 256 + t;            // 0..1023
            int r = idx >> 4, s = idx & 15;   // K: 64 rows x 16 slots
            gl2lds16(Kc + (size_t)(kv0 + r) * HID + h * HD + ((s ^ (r & 7)) << 3),
                     (void*)(&Kb[buf][(i * 256 + w * 64) << 3]));
            int r2 = idx >> 3, s2 = idx & 7;  // VT: 128 rows x 8 slots
            gl2lds16(VT + (size_t)(h * HD + r2) * SQ + kv0 + ((s2 ^ (r2 & 7)) << 3),
                     (void*)(&Vb[buf][(i * 256 + w * 64) << 3]));
        }
    };

    int strips[2] = {bx, 63 - bx};
    for (int sp = 0; sp < 2; sp++) {
        int qbase = strips[sp] * 64;
        int wq0 = qbase + w * 16;

        stage(0, 0);
        bf16x8 qf[4];
        {
            int qrow = wq0 + lr;
            for (int ks = 0; ks < 4; ks++)
                qf[ks] = *(const bf16x8*)(Q + (size_t)qrow * HID + h * HD + ks * 32 + (hi << 3));
        }
        f32x4 o_acc[8] = {};
        float m_r[4], l_r[4];
        for (int r = 0; r < 4; r++) { m_r[r] = -1e30f; l_r[r] = 0.f; }
        __syncthreads();

        int nt = strips[sp] + 1;     // KV tiles for this strip
        int cur = 0;
        for (int tile = 0; tile < nt; tile++) {
            int kv0 = tile * 64;
            if (tile + 1 < nt) stage(cur ^ 1, kv0 + 64);   // async prefetch
            const unsigned short* Kl = &Kb[cur][0];
            const unsigned short* Vl = &Vb[cur][0];

            if (kv0 <= wq0 + 15) {   // not fully above this wave's diagonal
                // S = Q K^T  (16 q-rows x 64 kv-cols), swizzled K reads
                f32x4 sfr[4];
                for (int c = 0; c < 4; c++) {
                    f32x4 s = {0.f, 0.f, 0.f, 0.f};
                    for (int ks = 0; ks < 4; ks++) {
                        bf16x8 kf = *(const bf16x8*)(Kl + (c * 16 + lr) * 128 +
                                                     (((ks * 4 + hi) ^ (lr & 7)) << 3));
                        s = __builtin_amdgcn_mfma_f32_16x16x32_bf16(qf[ks], kf, s, 0, 0, 0);
                    }
                    sfr[c] = s;
                }
                // scale + causal mask (only tiles straddling the diagonal)
                int rq = wq0 + (hi << 2);
                if (kv0 + 63 > wq0) {
                    for (int c = 0; c < 4; c++) {
                        int kcol = kv0 + c * 16 + lr;
                        for (int r = 0; r < 4; r++) {
                            float v = sfr[c][r] * scale;
                            sfr[c][r] = (kcol <= rq + r) ? v : -1e30f;
                        }
                    }
                } else {
                    for (int c = 0; c < 4; c++)
                        for (int r = 0; r < 4; r++) sfr[c][r] *= scale;
                }
                // online softmax
                float alpha[4];
                for (int r = 0; r < 4; r++) {
                    float v = fmaxf(fmaxf(sfr[0][r], sfr[1][r]), fmaxf(sfr[2][r], sfr[3][r]));
                    v = fmaxf(v, __shfl_xor(v, 1));
                    v = fmaxf(v, __shfl_xor(v, 2));
                    v = fmaxf(v, __shfl_xor(v, 4));
                    v = fmaxf(v, __shfl_xor(v, 8));
                    float mn = fmaxf(m_r[r], v);
                    alpha[r] = __expf(m_r[r] - mn);
                    m_r[r] = mn;
                }
                float rs[4] = {0.f, 0.f, 0.f, 0.f};
                for (int c = 0; c < 4; c++)
                    for (int r = 0; r < 4; r++) {
                        float p = __expf(sfr[c][r] - m_r[r]);
                        sfr[c][r] = p;
                        rs[r] += p;
                    }
                for (int r = 0; r < 4; r++) {
                    float v = rs[r];
                    v += __shfl_xor(v, 1); v += __shfl_xor(v, 2);
                    v += __shfl_xor(v, 4); v += __shfl_xor(v, 8);
                    l_r[r] = l_r[r] * alpha[r] + v;
                }
                for (int c2 = 0; c2 < 8; c2++)
                    for (int r = 0; r < 4; r++) o_acc[c2][r] *= alpha[r];

                // P -> per-wave LDS buffer (swizzled), re-fragment for PV A-op
                unsigned short* pw = &Pt[w][0];
                for (int c = 0; c < 4; c++)
                    for (int r = 0; r < 4; r++) {
                        int row = (hi << 2) + r;
                        int sslot = c * 2 + (lr >> 3);
                        pw[row * 64 + ((sslot ^ (row & 7)) << 3) + (lr & 7)] = f2bf(sfr[c][r]);
                    }
                asm volatile("s_waitcnt lgkmcnt(0)" ::: "memory");

                // O += P V (A = P [16x64], B = V via VT LDS), swizzled
                for (int kk = 0; kk < 2; kk++) {
                    bf16x8 pa = *(const bf16x8*)(pw + lr * 64 +
                                                 (((kk * 4 + hi) ^ (lr & 7)) << 3));
                    for (int c2 = 0; c2 < 8; c2++) {
                        bf16x8 bv = *(const bf16x8*)(Vl + (c2 * 16 + lr) * 64 +
                                                     (((kk * 4 + hi) ^ (lr & 7)) << 3));
                        o_acc[c2] = __builtin_amdgcn_mfma_f32_16x16x32_bf16(pa, bv, o_acc[c2], 0, 0, 0);
                    }
                }
            }
            __syncthreads();   // drains prefetch vmcnt + syncs buffer flip
            cur ^= 1;
        }

        for (int c2 = 0; c2 < 8; c2++)
            for (int r = 0; r < 4; r++) {
                int row = wq0 + (hi << 2) + r;
                O[(size_t)row * HID + h * HD + c2 * 16 + lr] = f2bf(o_acc[c2][r] / l_r[r]);
            }
        __syncthreads();   // strip boundary: all waves done before re-staging Kb[0]
    }
}

// ---------------------------------------------------------------------------
extern "C" void kernel_launch(void* const* d_in, const int* in_sizes, int n_in,
                              void* d_out, int out_size, void* d_ws, size_t ws_size,
                              hipStream_t stream) {
    const float* x  = (const float*)d_in[0];
    const float* Wq = (const float*)d_in[1];
    const float* bq = (const float*)d_in[2];
    const float* Wk = (const float*)d_in[3];
    const float* bk = (const float*)d_in[4];
    const float* Wv = (const float*)d_in[5];
    const float* bv = (const float*)d_in[6];
    const float* Wo = (const float*)d_in[7];

    char* ws = (char*)d_ws;
    const size_t MB = 1024 * 1024;
    unsigned short* xb  = (unsigned short*)(ws + 0 * MB);
    unsigned short* WqT = (unsigned short*)(ws + 16 * MB);
    unsigned short* WkT = (unsigned short*)(ws + 24 * MB);
    unsigned short* WvT = (unsigned short*)(ws + 32 * MB);
    unsigned short* WoT = (unsigned short*)(ws + 40 * MB);
    unsigned short* Qb  = (unsigned short*)(ws + 48 * MB);
    unsigned short* Kbuf= (unsigned short*)(ws + 64 * MB);
    unsigned short* VTb = (unsigned short*)(ws + 80 * MB);
    unsigned short* Ctx = (unsigned short*)(ws + 96 * MB);

    // 1. x -> bf16
    cvt_f32_bf16<<<8192, 256, 0, stream>>>(x, xb, SQ * HID);
    // 2. weights -> transposed bf16
    dim3 tg(HID / 64, HID / 64);
    transcvt<<<tg, 256, 0, stream>>>(Wq, WqT);
    transcvt<<<tg, 256, 0, stream>>>(Wk, WkT);
    transcvt<<<tg, 256, 0, stream>>>(Wv, WvT);
    transcvt<<<tg, 256, 0, stream>>>(Wo, WoT);
    // 3. QKV projections
    dim3 gg(SQ / 128, HID / 128);
    gemm_bf16<0><<<gg, 256, 0, stream>>>(xb, WqT, bq, (void*)Qb);
    gemm_bf16<0><<<gg, 256, 0, stream>>>(xb, WkT, bk, (void*)Kbuf);
    gemm_bf16<1><<<gg, 256, 0, stream>>>(xb, WvT, bv, (void*)VTb);  // V stored transposed
    // 4. causal attention
    attn<<<dim3(NH, 32), 256, 0, stream>>>(Qb, Kbuf, VTb, Ctx);
    // 5. output projection (fp32 out, no bias)
    gemm_bf16<2><<<gg, 256, 0, stream>>>(Ctx, WoT, nullptr, d_out);
}

// Round 5
// 382.580 us; speedup vs baseline: 1.0626x; 1.0626x over previous
//
#include <hip/hip_runtime.h>
#include <hip/hip_bf16.h>
#include <stdint.h>

// Problem: B=1, S=4096, HIDDEN=2048, HEADS=16, HEAD_DIM=128, causal MHA.
// All inputs fp32; output fp32. Compute in bf16 MFMA with fp32 accum.
//
// Workspace layout (bytes), total ~112 MB:
//   xb   [4096][2048] bf16 @ 0          (16 MB)
//   WqT  [2048][2048] bf16 @ 16 MB      (8 MB)   (transposed: [out][in])
//   WkT  @ 24 MB, WvT @ 32 MB, WoT @ 40 MB
//   Qb   [4096][2048] bf16 @ 48 MB
//   Kb   [4096][2048] bf16 @ 64 MB
//   VTb  [2048][4096] bf16 @ 80 MB      (V transposed per-head: row h*128+d, col s)
//   Ctx  [4096][2048] bf16 @ 96 MB

#define SQ 4096
#define HID 2048
#define NH 16
#define HD 128

typedef __attribute__((ext_vector_type(8))) short bf16x8;
typedef __attribute__((ext_vector_type(4))) float f32x4;
typedef __attribute__((ext_vector_type(4))) unsigned short us4;

__device__ inline unsigned short f2bf(float f) {
    unsigned int u = __builtin_bit_cast(unsigned int, f);
    u = (u + 0x7FFFu + ((u >> 16) & 1u)) >> 16;
    return (unsigned short)u;
}

__device__ inline void gl2lds16(const void* g, void* l) {
    __builtin_amdgcn_global_load_lds(
        (const __attribute__((address_space(1))) unsigned int*)g,
        (__attribute__((address_space(3))) unsigned int*)l, 16, 0, 0);
}

// ---------------- fp32 -> bf16 convert (grid-stride, float4) ----------------
__global__ void cvt_f32_bf16(const float* __restrict__ src,
                             unsigned short* __restrict__ dst, int n) {
    int i = (blockIdx.x * blockDim.x + threadIdx.x) * 4;
    int stride = gridDim.x * blockDim.x * 4;
    for (; i < n; i += stride) {
        float4 v = *(const float4*)(src + i);
        us4 o;
        o.x = f2bf(v.x); o.y = f2bf(v.y); o.z = f2bf(v.z); o.w = f2bf(v.w);
        *(us4*)(dst + i) = o;
    }
}

// -------- transpose + convert: W [K][N] f32 -> WT [N][K] bf16 (2048x2048) ---
__global__ void transcvt(const float* __restrict__ W, unsigned short* __restrict__ WT) {
    __shared__ float tile[64][65];
    int n0 = blockIdx.x * 64, k0 = blockIdx.y * 64;
    int t = threadIdx.x;
    for (int i = 0; i < 4; i++) {
        int idx = i * 256 + t;          // 0..1023
        int k = idx >> 4;               // 64 rows, 16 float4 per row
        int n4 = (idx & 15) << 2;
        float4 v = *(const float4*)(W + (size_t)(k0 + k) * HID + n0 + n4);
        tile[k][n4 + 0] = v.x; tile[k][n4 + 1] = v.y;
        tile[k][n4 + 2] = v.z; tile[k][n4 + 3] = v.w;
    }
    __syncthreads();
    for (int i = 0; i < 4; i++) {
        int idx = i * 256 + t;
        int n = idx >> 4;
        int k4 = (idx & 15) << 2;
        us4 o;
        o.x = f2bf(tile[k4 + 0][n]); o.y = f2bf(tile[k4 + 1][n]);
        o.z = f2bf(tile[k4 + 2][n]); o.w = f2bf(tile[k4 + 3][n]);
        *(us4*)(WT + (size_t)(n0 + n) * HID + k0 + k4) = o;
    }
}

// ---------------- bf16 GEMM: C[M,N] = A[M,K] @ BT[N,K]^T (+bias) ------------
// M=4096, N=2048, K=2048. 128x128 tile, BK=64, 256 thr = 4 waves (2x2 of 64x64).
// OUTMODE 0: bf16 out [M][N] + bias; 1: bf16 out transposed [N][M] + bias;
//         2: f32 out [M][N], no bias.
template <int OUTMODE>
__global__ __launch_bounds__(256) void gemm_bf16(
    const unsigned short* __restrict__ A, const unsigned short* __restrict__ BT,
    const float* __restrict__ bias, void* __restrict__ C) {
    const int M = 4096, N = 2048, K = 2048;
    __shared__ __align__(16) unsigned short As[128 * 64];
    __shared__ __align__(16) unsigned short Bs[128 * 64];
    int m0 = blockIdx.x * 128, n0 = blockIdx.y * 128;
    int t = threadIdx.x;
    int lane = t & 63, wid = t >> 6;
    int wm = wid >> 1, wn = wid & 1;
    f32x4 acc[4][4] = {};

    for (int k0 = 0; k0 < K; k0 += 64) {
        for (int i = 0; i < 4; i++) {
            int idx = i * 256 + t;           // 1024 x 16B loads per tile
            int r = idx >> 3;                // row 0..127 (8 loads of 8 elems per row)
            int c = (idx & 7) << 3;
            void* ldsA = (void*)(As + ((i * 256 + wid * 64) << 3));
            void* ldsB = (void*)(Bs + ((i * 256 + wid * 64) << 3));
            gl2lds16(A + (size_t)(m0 + r) * K + k0 + c, ldsA);
            gl2lds16(BT + (size_t)(n0 + r) * K + k0 + c, ldsB);
        }
        __syncthreads();
        for (int kk = 0; kk < 2; kk++) {
            int ko = kk * 32 + ((lane >> 4) << 3);
            bf16x8 af[4], bfg[4];
            for (int mf = 0; mf < 4; mf++)
                af[mf] = *(const bf16x8*)(As + (wm * 64 + mf * 16 + (lane & 15)) * 64 + ko);
            for (int nf = 0; nf < 4; nf++)
                bfg[nf] = *(const bf16x8*)(Bs + (wn * 64 + nf * 16 + (lane & 15)) * 64 + ko);
            for (int mf = 0; mf < 4; mf++)
                for (int nf = 0; nf < 4; nf++)
                    acc[mf][nf] = __builtin_amdgcn_mfma_f32_16x16x32_bf16(
                        af[mf], bfg[nf], acc[mf][nf], 0, 0, 0);
        }
        __syncthreads();
    }

    int rbase = (lane >> 4) << 2;
    for (int mf = 0; mf < 4; mf++) {
        for (int nf = 0; nf < 4; nf++) {
            int n_g = n0 + wn * 64 + nf * 16 + (lane & 15);
            int m_base = m0 + wm * 64 + mf * 16 + rbase;
            float b = (OUTMODE == 2) ? 0.f : bias[n_g];
            if (OUTMODE == 0) {
                unsigned short* Cb = (unsigned short*)C;
                for (int r = 0; r < 4; r++)
                    Cb[(size_t)(m_base + r) * N + n_g] = f2bf(acc[mf][nf][r] + b);
            } else if (OUTMODE == 1) {
                unsigned short* Cb = (unsigned short*)C;
                us4 o;
                o.x = f2bf(acc[mf][nf][0] + b); o.y = f2bf(acc[mf][nf][1] + b);
                o.z = f2bf(acc[mf][nf][2] + b); o.w = f2bf(acc[mf][nf][3] + b);
                *(us4*)(Cb + (size_t)n_g * M + m_base) = o;
            } else {
                float* Cf = (float*)C;
                for (int r = 0; r < 4; r++)
                    Cf[(size_t)(m_base + r) * N + n_g] = acc[mf][nf][r];
            }
        }
    }
}

// ---------------- causal flash attention (v5: swapped QK^T, in-reg softmax) --
// grid (NH, 32); 256 thr = 4 waves; QBLK=64 (wave w owns q rows qbase+w*16..+15).
// Block (h, bx) processes q-strips bx and 63-bx -> exactly 65 KV-tiles/block.
// SWAPPED math: S^T = mfma(K, Q) so lane owns q = lane&15; in-lane softmax
// (15 fmax + 2 shfl_xor); P stays in registers (cvt_pk_bf16 + 16 shfl
// re-fragment as PV B-operand); O^T = V^T @ P^T accumulated; transpose via
// LDS scratch once per strip. No P LDS round-trip at all.
__global__ __launch_bounds__(256) void attn(
    const unsigned short* __restrict__ Q, const unsigned short* __restrict__ Kc,
    const unsigned short* __restrict__ VT, unsigned short* __restrict__ O) {
    __shared__ __align__(16) unsigned short SMEM[32768];   // 64 KB
    unsigned short* KB = SMEM;              // [2][64*128]
    unsigned short* VB = SMEM + 16384;      // [2][128*64]
    int h = blockIdx.x;
    int bx = blockIdx.y;
    int t = threadIdx.x, lane = t & 63, w = t >> 6;
    int lr = lane & 15, hi = lane >> 4;
    const float scale = 0.08838834764831845f;  // 1/sqrt(128)

    // stage K/V tile kv0 into buffer `buf`, swizzled source (linear LDS dest).
    auto stage = [&](int buf, int kv0) {
        for (int i = 0; i < 4; i++) {
            int idx = i * 256 + t;            // 0..1023
            int r = idx >> 4, s = idx & 15;   // K: 64 rows x 16 slots
            gl2lds16(Kc + (size_t)(kv0 + r) * HID + h * HD + ((s ^ (r & 7)) << 3),
                     (void*)(KB + buf * 8192 + ((i * 256 + w * 64) << 3)));
            int r2 = idx >> 3, s2 = idx & 7;  // VT: 128 rows x 8 slots
            gl2lds16(VT + (size_t)(h * HD + r2) * SQ + kv0 + ((s2 ^ (r2 & 7)) << 3),
                     (void*)(VB + buf * 8192 + ((i * 256 + w * 64) << 3)));
        }
    };

    int strips[2] = {bx, 63 - bx};
    for (int sp = 0; sp < 2; sp++) {
        int qbase = strips[sp] * 64;
        int wq0 = qbase + w * 16;
        int qg = wq0 + lr;                 // this lane's q row

        stage(0, 0);
        bf16x8 qf[4];
        for (int ks = 0; ks < 4; ks++)
            qf[ks] = *(const bf16x8*)(Q + (size_t)qg * HID + h * HD + ks * 32 + (hi << 3));
        f32x4 o_acc[8] = {};               // O^T frags: d=16c2+4hi+reg, q=lane&15
        float m_r = -1e30f, l_r = 0.f;     // per-lane scalars (one q row)
        __syncthreads();

        int nt = strips[sp] + 1;           // KV tiles for this strip
        int cur = 0;
        for (int tile = 0; tile < nt; tile++) {
            int kv0 = tile * 64;
            if (tile + 1 < nt) stage(cur ^ 1, kv0 + 64);   // async prefetch
            const unsigned short* Kl = KB + cur * 8192;
            const unsigned short* Vl = VB + cur * 8192;

            if (kv0 <= wq0 + 15) {   // not fully above this wave's diagonal
                // S^T = mfma(K, Q): sfr[c][r] = S^T[k=16c+4hi+r][q=lane&15]
                f32x4 sfr[4];
                for (int c = 0; c < 4; c++) {
                    f32x4 s = {0.f, 0.f, 0.f, 0.f};
                    for (int ks = 0; ks < 4; ks++) {
                        bf16x8 kf = *(const bf16x8*)(Kl + (c * 16 + lr) * 128 +
                                                     (((ks * 4 + hi) ^ (lr & 7)) << 3));
                        s = __builtin_amdgcn_mfma_f32_16x16x32_bf16(kf, qf[ks], s, 0, 0, 0);
                    }
                    sfr[c] = s;
                }
                // scale + causal mask (k_g <= q_g)
                if (kv0 + 63 > wq0) {
                    for (int c = 0; c < 4; c++) {
                        int kgb = kv0 + c * 16 + 4 * hi;
                        for (int r = 0; r < 4; r++) {
                            float v = sfr[c][r] * scale;
                            sfr[c][r] = (kgb + r <= qg) ? v : -1e30f;
                        }
                    }
                } else {
                    for (int c = 0; c < 4; c++)
                        for (int r = 0; r < 4; r++) sfr[c][r] *= scale;
                }
                // in-lane row max (16 values) + cross-hi (2 shfl_xor)
                float mx = fmaxf(fmaxf(fmaxf(sfr[0][0], sfr[0][1]), fmaxf(sfr[0][2], sfr[0][3])),
                                 fmaxf(fmaxf(sfr[1][0], sfr[1][1]), fmaxf(sfr[1][2], sfr[1][3])));
                float mx2 = fmaxf(fmaxf(fmaxf(sfr[2][0], sfr[2][1]), fmaxf(sfr[2][2], sfr[2][3])),
                                  fmaxf(fmaxf(sfr[3][0], sfr[3][1]), fmaxf(sfr[3][2], sfr[3][3])));
                mx = fmaxf(mx, mx2);
                mx = fmaxf(mx, __shfl_xor(mx, 16));
                mx = fmaxf(mx, __shfl_xor(mx, 32));
                float mn = fmaxf(m_r, mx);
                float alpha = __expf(m_r - mn);
                m_r = mn;
                // exp + row sum
                float rs = 0.f;
                for (int c = 0; c < 4; c++)
                    for (int r = 0; r < 4; r++) {
                        float p = __expf(sfr[c][r] - mn);
                        sfr[c][r] = p;
                        rs += p;
                    }
                rs += __shfl_xor(rs, 16);
                rs += __shfl_xor(rs, 32);
                l_r = l_r * alpha + rs;
                for (int c2 = 0; c2 < 8; c2++)
                    for (int r = 0; r < 4; r++) o_acc[c2][r] *= alpha;

                // P^T -> PV B-operand fragments, fully in-register.
                // wpk[c][i] = bf16 pair (P^T[16c+4hi+2i], [..+2i+1]) for q=lane&15
                unsigned int wpk[4][2];
#pragma unroll
                for (int c = 0; c < 4; c++)
#pragma unroll
                    for (int i = 0; i < 2; i++) {
                        unsigned int d;
                        asm("v_cvt_pk_bf16_f32 %0, %1, %2"
                            : "=v"(d) : "v"(sfr[c][2 * i]), "v"(sfr[c][2 * i + 1]));
                        wpk[c][i] = d;
                    }
                // B-frag for mfma kk: lane needs P^T[k=32kk+8hi+j][q], j=0..7.
                // sources: lane (q, hi_s=2(hi&1)) slots 0,1; (q, hi_s+1) slots 2,3;
                // c_src = 2kk + (hi>>1)  (dual-shfl + select, static indexing)
                int srcA = lr + ((hi & 1) << 5);
                int srcB = srcA + 16;
                bool sel = (hi & 2);
#pragma unroll
                for (int kk = 0; kk < 2; kk++) {
                    unsigned int a0 = __shfl(wpk[2 * kk][0], srcA);
                    unsigned int a1 = __shfl(wpk[2 * kk][1], srcA);
                    unsigned int a2 = __shfl(wpk[2 * kk][0], srcB);
                    unsigned int a3 = __shfl(wpk[2 * kk][1], srcB);
                    unsigned int b0 = __shfl(wpk[2 * kk + 1][0], srcA);
                    unsigned int b1 = __shfl(wpk[2 * kk + 1][1], srcA);
                    unsigned int b2 = __shfl(wpk[2 * kk + 1][0], srcB);
                    unsigned int b3 = __shfl(wpk[2 * kk + 1][1], srcB);
                    union { unsigned int u[4]; bf16x8 v; } pf;
                    pf.u[0] = sel ? b0 : a0;
                    pf.u[1] = sel ? b1 : a1;
                    pf.u[2] = sel ? b2 : a2;
                    pf.u[3] = sel ? b3 : a3;
                    // O^T += V^T @ P^T : A = V^T (rows d), B = P^T frag
                    for (int c2 = 0; c2 < 8; c2++) {
                        bf16x8 vv = *(const bf16x8*)(Vl + (c2 * 16 + lr) * 64 +
                                                     (((kk * 4 + hi) ^ (lr & 7)) << 3));
                        o_acc[c2] = __builtin_amdgcn_mfma_f32_16x16x32_bf16(
                            vv, pf.v, o_acc[c2], 0, 0, 0);
                    }
                }
            }
            __syncthreads();   // drains prefetch vmcnt + syncs buffer flip
            cur ^= 1;
        }

        // strip epilogue: transpose O^T->O via LDS scratch (SMEM is free now)
        __syncthreads();
        float* tb = (float*)SMEM;          // per-wave region: 16 rows x 132 f32
        float invl = 1.0f / l_r;
        int base = w * 2112 + lr * 132;    // row q=lr (this lane's q)
        for (int c2 = 0; c2 < 8; c2++)
            for (int r = 0; r < 4; r++)
                tb[base + 16 * c2 + 4 * hi + r] = o_acc[c2][r] * invl;
        __syncthreads();
        for (int i = 0; i < 8; i++) {
            int d4 = hi + 4 * i;           // float4 chunk 0..31
            f32x4 v = *(const f32x4*)&tb[w * 2112 + lr * 132 + d4 * 4];
            us4 o;
            o.x = f2bf(v[0]); o.y = f2bf(v[1]); o.z = f2bf(v[2]); o.w = f2bf(v[3]);
            *(us4*)(O + (size_t)qg * HID + h * HD + d4 * 4) = o;
        }
        __syncthreads();   // before next strip re-stages into SMEM
    }
}

// ---------------------------------------------------------------------------
extern "C" void kernel_launch(void* const* d_in, const int* in_sizes, int n_in,
                              void* d_out, int out_size, void* d_ws, size_t ws_size,
                              hipStream_t stream) {
    const float* x  = (const float*)d_in[0];
    const float* Wq = (const float*)d_in[1];
    const float* bq = (const float*)d_in[2];
    const float* Wk = (const float*)d_in[3];
    const float* bk = (const float*)d_in[4];
    const float* Wv = (const float*)d_in[5];
    const float* bv = (const float*)d_in[6];
    const float* Wo = (const float*)d_in[7];

    char* ws = (char*)d_ws;
    const size_t MB = 1024 * 1024;
    unsigned short* xb  = (unsigned short*)(ws + 0 * MB);
    unsigned short* WqT = (unsigned short*)(ws + 16 * MB);
    unsigned short* WkT = (unsigned short*)(ws + 24 * MB);
    unsigned short* WvT = (unsigned short*)(ws + 32 * MB);
    unsigned short* WoT = (unsigned short*)(ws + 40 * MB);
    unsigned short* Qb  = (unsigned short*)(ws + 48 * MB);
    unsigned short* Kbuf= (unsigned short*)(ws + 64 * MB);
    unsigned short* VTb = (unsigned short*)(ws + 80 * MB);
    unsigned short* Ctx = (unsigned short*)(ws + 96 * MB);

    // 1. x -> bf16
    cvt_f32_bf16<<<8192, 256, 0, stream>>>(x, xb, SQ * HID);
    // 2. weights -> transposed bf16
    dim3 tg(HID / 64, HID / 64);
    transcvt<<<tg, 256, 0, stream>>>(Wq, WqT);
    transcvt<<<tg, 256, 0, stream>>>(Wk, WkT);
    transcvt<<<tg, 256, 0, stream>>>(Wv, WvT);
    transcvt<<<tg, 256, 0, stream>>>(Wo, WoT);
    // 3. QKV projections
    dim3 gg(SQ / 128, HID / 128);
    gemm_bf16<0><<<gg, 256, 0, stream>>>(xb, WqT, bq, (void*)Qb);
    gemm_bf16<0><<<gg, 256, 0, stream>>>(xb, WkT, bk, (void*)Kbuf);
    gemm_bf16<1><<<gg, 256, 0, stream>>>(xb, WvT, bv, (void*)VTb);  // V stored transposed
    // 4. causal attention
    attn<<<dim3(NH, 32), 256, 0, stream>>>(Qb, Kbuf, VTb, Ctx);
    // 5. output projection (fp32 out, no bias)
    gemm_bf16<2><<<gg, 256, 0, stream>>>(Ctx, WoT, nullptr, d_out);
}

// Round 6
// 354.991 us; speedup vs baseline: 1.1452x; 1.0777x over previous
//
#include <hip/hip_runtime.h>
#include <hip/hip_bf16.h>
#include <stdint.h>

// Problem: B=1, S=4096, HIDDEN=2048, HEADS=16, HEAD_DIM=128, causal MHA.
// All inputs fp32; output fp32. Compute in bf16 MFMA with fp32 accum.
//
// Workspace layout (bytes), total ~112 MB:
//   xb    [4096][2048] bf16 @ 0         (16 MB)
//   WTall [4][2048][2048] bf16 @ 16 MB  (32 MB: WqT,WkT,WvT,WoT transposed [out][in])
//   Qb    [4096][2048] bf16 @ 48 MB
//   Kb    [4096][2048] bf16 @ 64 MB
//   VTb   [2048][4096] bf16 @ 80 MB     (V transposed per-head: row h*128+d, col s)
//   Ctx   [4096][2048] bf16 @ 96 MB

#define SQ 4096
#define HID 2048
#define NH 16
#define HD 128

typedef __attribute__((ext_vector_type(8))) short bf16x8;
typedef __attribute__((ext_vector_type(4))) float f32x4;
typedef __attribute__((ext_vector_type(4))) unsigned short us4;

__device__ inline unsigned short f2bf(float f) {
    unsigned int u = __builtin_bit_cast(unsigned int, f);
    u = (u + 0x7FFFu + ((u >> 16) & 1u)) >> 16;
    return (unsigned short)u;
}

__device__ inline void gl2lds16(const void* g, void* l) {
    __builtin_amdgcn_global_load_lds(
        (const __attribute__((address_space(1))) unsigned int*)g,
        (__attribute__((address_space(3))) unsigned int*)l, 16, 0, 0);
}

// ---------------- fp32 -> bf16 convert (grid-stride, float4) ----------------
__global__ void cvt_f32_bf16(const float* __restrict__ src,
                             unsigned short* __restrict__ dst, int n) {
    int i = (blockIdx.x * blockDim.x + threadIdx.x) * 4;
    int stride = gridDim.x * blockDim.x * 4;
    for (; i < n; i += stride) {
        float4 v = *(const float4*)(src + i);
        us4 o;
        o.x = f2bf(v.x); o.y = f2bf(v.y); o.z = f2bf(v.z); o.w = f2bf(v.w);
        *(us4*)(dst + i) = o;
    }
}

// ---- transpose + convert all 4 weights: W [K][N] f32 -> WT [N][K] bf16 -----
__global__ void transcvt4(const float* __restrict__ W0, const float* __restrict__ W1,
                          const float* __restrict__ W2, const float* __restrict__ W3,
                          unsigned short* __restrict__ WTall) {
    __shared__ float tile[64][65];
    const float* W = (blockIdx.z == 0) ? W0 : (blockIdx.z == 1) ? W1
                   : (blockIdx.z == 2) ? W2 : W3;
    unsigned short* WT = WTall + (size_t)blockIdx.z * HID * HID;
    int n0 = blockIdx.x * 64, k0 = blockIdx.y * 64;
    int t = threadIdx.x;
    for (int i = 0; i < 4; i++) {
        int idx = i * 256 + t;          // 0..1023
        int k = idx >> 4;               // 64 rows, 16 float4 per row
        int n4 = (idx & 15) << 2;
        float4 v = *(const float4*)(W + (size_t)(k0 + k) * HID + n0 + n4);
        tile[k][n4 + 0] = v.x; tile[k][n4 + 1] = v.y;
        tile[k][n4 + 2] = v.z; tile[k][n4 + 3] = v.w;
    }
    __syncthreads();
    for (int i = 0; i < 4; i++) {
        int idx = i * 256 + t;
        int n = idx >> 4;
        int k4 = (idx & 15) << 2;
        us4 o;
        o.x = f2bf(tile[k4 + 0][n]); o.y = f2bf(tile[k4 + 1][n]);
        o.z = f2bf(tile[k4 + 2][n]); o.w = f2bf(tile[k4 + 3][n]);
        *(us4*)(WT + (size_t)(n0 + n) * HID + k0 + k4) = o;
    }
}

// ---------------- fused QKV GEMM: 3 projections in one dispatch -------------
// grid (32, 48): proj = by>>4 (0=Q,1=K,2=V), n0 = (by&15)*128. 128x128 tile,
// BK=64, 256 thr = 4 waves. Q/K: bf16 [M][N] + bias. V: bf16 [N][M] + bias.
__global__ __launch_bounds__(256) void gemm_qkv(
    const unsigned short* __restrict__ A, const unsigned short* __restrict__ WTall,
    const float* __restrict__ bq, const float* __restrict__ bk,
    const float* __restrict__ bv, unsigned short* __restrict__ Qb,
    unsigned short* __restrict__ Kb, unsigned short* __restrict__ VTb) {
    const int M = 4096, N = 2048, K = 2048;
    __shared__ __align__(16) unsigned short As[128 * 64];
    __shared__ __align__(16) unsigned short Bs[128 * 64];
    int proj = blockIdx.y >> 4;
    int m0 = blockIdx.x * 128, n0 = (blockIdx.y & 15) * 128;
    const unsigned short* BT = WTall + (size_t)proj * HID * HID;
    int t = threadIdx.x;
    int lane = t & 63, wid = t >> 6;
    int wm = wid >> 1, wn = wid & 1;
    f32x4 acc[4][4] = {};

    for (int k0 = 0; k0 < K; k0 += 64) {
        for (int i = 0; i < 4; i++) {
            int idx = i * 256 + t;
            int r = idx >> 3;
            int c = (idx & 7) << 3;
            void* ldsA = (void*)(As + ((i * 256 + wid * 64) << 3));
            void* ldsB = (void*)(Bs + ((i * 256 + wid * 64) << 3));
            gl2lds16(A + (size_t)(m0 + r) * K + k0 + c, ldsA);
            gl2lds16(BT + (size_t)(n0 + r) * K + k0 + c, ldsB);
        }
        __syncthreads();
        for (int kk = 0; kk < 2; kk++) {
            int ko = kk * 32 + ((lane >> 4) << 3);
            bf16x8 af[4], bfg[4];
            for (int mf = 0; mf < 4; mf++)
                af[mf] = *(const bf16x8*)(As + (wm * 64 + mf * 16 + (lane & 15)) * 64 + ko);
            for (int nf = 0; nf < 4; nf++)
                bfg[nf] = *(const bf16x8*)(Bs + (wn * 64 + nf * 16 + (lane & 15)) * 64 + ko);
            for (int mf = 0; mf < 4; mf++)
                for (int nf = 0; nf < 4; nf++)
                    acc[mf][nf] = __builtin_amdgcn_mfma_f32_16x16x32_bf16(
                        af[mf], bfg[nf], acc[mf][nf], 0, 0, 0);
        }
        __syncthreads();
    }

    const float* bias = (proj == 0) ? bq : (proj == 1) ? bk : bv;
    int rbase = (lane >> 4) << 2;
    for (int mf = 0; mf < 4; mf++) {
        for (int nf = 0; nf < 4; nf++) {
            int n_g = n0 + wn * 64 + nf * 16 + (lane & 15);
            int m_base = m0 + wm * 64 + mf * 16 + rbase;
            float b = bias[n_g];
            if (proj < 2) {
                unsigned short* Cb = proj ? Kb : Qb;
                for (int r = 0; r < 4; r++)
                    Cb[(size_t)(m_base + r) * N + n_g] = f2bf(acc[mf][nf][r] + b);
            } else {
                us4 o;
                o.x = f2bf(acc[mf][nf][0] + b); o.y = f2bf(acc[mf][nf][1] + b);
                o.z = f2bf(acc[mf][nf][2] + b); o.w = f2bf(acc[mf][nf][3] + b);
                *(us4*)(VTb + (size_t)n_g * M + m_base) = o;
            }
        }
    }
}

// ---------------- o-proj GEMM: f32 out, no bias ------------------------------
__global__ __launch_bounds__(256) void gemm_out(
    const unsigned short* __restrict__ A, const unsigned short* __restrict__ BT,
    float* __restrict__ C) {
    const int M = 4096, N = 2048, K = 2048;
    __shared__ __align__(16) unsigned short As[128 * 64];
    __shared__ __align__(16) unsigned short Bs[128 * 64];
    int m0 = blockIdx.x * 128, n0 = blockIdx.y * 128;
    int t = threadIdx.x;
    int lane = t & 63, wid = t >> 6;
    int wm = wid >> 1, wn = wid & 1;
    f32x4 acc[4][4] = {};

    for (int k0 = 0; k0 < K; k0 += 64) {
        for (int i = 0; i < 4; i++) {
            int idx = i * 256 + t;
            int r = idx >> 3;
            int c = (idx & 7) << 3;
            void* ldsA = (void*)(As + ((i * 256 + wid * 64) << 3));
            void* ldsB = (void*)(Bs + ((i * 256 + wid * 64) << 3));
            gl2lds16(A + (size_t)(m0 + r) * K + k0 + c, ldsA);
            gl2lds16(BT + (size_t)(n0 + r) * K + k0 + c, ldsB);
        }
        __syncthreads();
        for (int kk = 0; kk < 2; kk++) {
            int ko = kk * 32 + ((lane >> 4) << 3);
            bf16x8 af[4], bfg[4];
            for (int mf = 0; mf < 4; mf++)
                af[mf] = *(const bf16x8*)(As + (wm * 64 + mf * 16 + (lane & 15)) * 64 + ko);
            for (int nf = 0; nf < 4; nf++)
                bfg[nf] = *(const bf16x8*)(Bs + (wn * 64 + nf * 16 + (lane & 15)) * 64 + ko);
            for (int mf = 0; mf < 4; mf++)
                for (int nf = 0; nf < 4; nf++)
                    acc[mf][nf] = __builtin_amdgcn_mfma_f32_16x16x32_bf16(
                        af[mf], bfg[nf], acc[mf][nf], 0, 0, 0);
        }
        __syncthreads();
    }

    int rbase = (lane >> 4) << 2;
    for (int mf = 0; mf < 4; mf++)
        for (int nf = 0; nf < 4; nf++) {
            int n_g = n0 + wn * 64 + nf * 16 + (lane & 15);
            int m_base = m0 + wm * 64 + mf * 16 + rbase;
            for (int r = 0; r < 4; r++)
                C[(size_t)(m_base + r) * N + n_g] = acc[mf][nf][r];
        }
}

// ---------------- causal flash attention (v6) --------------------------------
// grid (NH, 32); 512 thr = 8 waves; QBLK=128 (wave w owns q rows strip*128 +
// w*16..+15). strip = 31 - by (heavy blocks dispatch first; scheduler
// backfills). 64 KB LDS -> 2 blocks/CU -> 16 waves/CU. All strips of head h
// map to XCD h%8 (id%8 heuristic, 16 ≡ 0 mod 8) -> per-XCD L2 holds 2 heads'
// K+V (4 MB) -> staging is L2-hit (verified round 3: FETCH 10x drop).
// Swapped math (v5): S^T = mfma(K,Q), lane owns q = lane&15; in-lane softmax;
// P in registers (cvt_pk + shfl); O^T += V^T @ P^T; T13 defer-max (THR=8);
// bf16 LDS scratch transpose in epilogue.
__global__ __launch_bounds__(512) void attn(
    const unsigned short* __restrict__ Q, const unsigned short* __restrict__ Kc,
    const unsigned short* __restrict__ VT, unsigned short* __restrict__ O) {
    __shared__ __align__(16) unsigned short SMEM[32768];   // 64 KB
    unsigned short* KB = SMEM;              // [2][64*128]
    unsigned short* VB = SMEM + 16384;      // [2][128*64]
    int h = blockIdx.x;
    int strip = 31 - (int)blockIdx.y;       // heavy first
    int t = threadIdx.x, lane = t & 63, w = t >> 6;
    int lr = lane & 15, hi = lane >> 4;
    const float scale = 0.08838834764831845f;  // 1/sqrt(128)

    // stage K/V tile kv0 into buffer `buf`, swizzled source (linear LDS dest).
    auto stage = [&](int buf, int kv0) {
        for (int i = 0; i < 2; i++) {
            int idx = i * 512 + t;            // 0..1023
            int r = idx >> 4, s = idx & 15;   // K: 64 rows x 16 slots
            gl2lds16(Kc + (size_t)(kv0 + r) * HID + h * HD + ((s ^ (r & 7)) << 3),
                     (void*)(KB + buf * 8192 + ((i * 512 + w * 64) << 3)));
            int r2 = idx >> 3, s2 = idx & 7;  // VT: 128 rows x 8 slots
            gl2lds16(VT + (size_t)(h * HD + r2) * SQ + kv0 + ((s2 ^ (r2 & 7)) << 3),
                     (void*)(VB + buf * 8192 + ((i * 512 + w * 64) << 3)));
        }
    };

    int qbase = strip * 128;
    int wq0 = qbase + w * 16;
    int qg = wq0 + lr;                 // this lane's q row

    stage(0, 0);
    bf16x8 qf[4];
    for (int ks = 0; ks < 4; ks++)
        qf[ks] = *(const bf16x8*)(Q + (size_t)qg * HID + h * HD + ks * 32 + (hi << 3));
    f32x4 o_acc[8] = {};               // O^T frags: d=16c2+4hi+reg, q=lane&15
    float m_r = -1e30f, l_r = 0.f;
    __syncthreads();

    int nt = 2 * strip + 2;            // KV tiles covering q rows of this strip
    int cur = 0;
    for (int tile = 0; tile < nt; tile++) {
        int kv0 = tile * 64;
        if (tile + 1 < nt) stage(cur ^ 1, kv0 + 64);   // async prefetch
        const unsigned short* Kl = KB + cur * 8192;
        const unsigned short* Vl = VB + cur * 8192;

        if (kv0 <= wq0 + 15) {   // not fully above this wave's diagonal
            // S^T = mfma(K, Q): sfr[c][r] = S^T[k=16c+4hi+r][q=lane&15]
            f32x4 sfr[4];
            for (int c = 0; c < 4; c++) {
                f32x4 s = {0.f, 0.f, 0.f, 0.f};
                for (int ks = 0; ks < 4; ks++) {
                    bf16x8 kf = *(const bf16x8*)(Kl + (c * 16 + lr) * 128 +
                                                 (((ks * 4 + hi) ^ (lr & 7)) << 3));
                    s = __builtin_amdgcn_mfma_f32_16x16x32_bf16(kf, qf[ks], s, 0, 0, 0);
                }
                sfr[c] = s;
            }
            // scale + causal mask (k_g <= q_g)
            if (kv0 + 63 > wq0) {
                for (int c = 0; c < 4; c++) {
                    int kgb = kv0 + c * 16 + 4 * hi;
                    for (int r = 0; r < 4; r++) {
                        float v = sfr[c][r] * scale;
                        sfr[c][r] = (kgb + r <= qg) ? v : -1e30f;
                    }
                }
            } else {
                for (int c = 0; c < 4; c++)
                    for (int r = 0; r < 4; r++) sfr[c][r] *= scale;
            }
            // in-lane row max (16 values) + cross-hi (2 shfl_xor)
            float mx = fmaxf(fmaxf(fmaxf(sfr[0][0], sfr[0][1]), fmaxf(sfr[0][2], sfr[0][3])),
                             fmaxf(fmaxf(sfr[1][0], sfr[1][1]), fmaxf(sfr[1][2], sfr[1][3])));
            float mx2 = fmaxf(fmaxf(fmaxf(sfr[2][0], sfr[2][1]), fmaxf(sfr[2][2], sfr[2][3])),
                              fmaxf(fmaxf(sfr[3][0], sfr[3][1]), fmaxf(sfr[3][2], sfr[3][3])));
            mx = fmaxf(mx, mx2);
            mx = fmaxf(mx, __shfl_xor(mx, 16));
            mx = fmaxf(mx, __shfl_xor(mx, 32));
            // T13 defer-max: skip rescale when tile max doesn't exceed m_r+8
            if (__all((mx - m_r) <= 8.0f)) {
                float rs = 0.f;
                for (int c = 0; c < 4; c++)
                    for (int r = 0; r < 4; r++) {
                        float p = __expf(sfr[c][r] - m_r);
                        sfr[c][r] = p;
                        rs += p;
                    }
                rs += __shfl_xor(rs, 16);
                rs += __shfl_xor(rs, 32);
                l_r += rs;
            } else {
                float mn = fmaxf(m_r, mx);
                float alpha = __expf(m_r - mn);
                m_r = mn;
                float rs = 0.f;
                for (int c = 0; c < 4; c++)
                    for (int r = 0; r < 4; r++) {
                        float p = __expf(sfr[c][r] - mn);
                        sfr[c][r] = p;
                        rs += p;
                    }
                rs += __shfl_xor(rs, 16);
                rs += __shfl_xor(rs, 32);
                l_r = l_r * alpha + rs;
                for (int c2 = 0; c2 < 8; c2++)
                    for (int r = 0; r < 4; r++) o_acc[c2][r] *= alpha;
            }

            // P^T -> PV B-operand fragments, fully in-register.
            unsigned int wpk[4][2];
#pragma unroll
            for (int c = 0; c < 4; c++)
#pragma unroll
                for (int i = 0; i < 2; i++) {
                    unsigned int d;
                    asm("v_cvt_pk_bf16_f32 %0, %1, %2"
                        : "=v"(d) : "v"(sfr[c][2 * i]), "v"(sfr[c][2 * i + 1]));
                    wpk[c][i] = d;
                }
            int srcA = lr + ((hi & 1) << 5);
            int srcB = srcA + 16;
            bool sel = (hi & 2);
#pragma unroll
            for (int kk = 0; kk < 2; kk++) {
                unsigned int a0 = __shfl(wpk[2 * kk][0], srcA);
                unsigned int a1 = __shfl(wpk[2 * kk][1], srcA);
                unsigned int a2 = __shfl(wpk[2 * kk][0], srcB);
                unsigned int a3 = __shfl(wpk[2 * kk][1], srcB);
                unsigned int b0 = __shfl(wpk[2 * kk + 1][0], srcA);
                unsigned int b1 = __shfl(wpk[2 * kk + 1][1], srcA);
                unsigned int b2 = __shfl(wpk[2 * kk + 1][0], srcB);
                unsigned int b3 = __shfl(wpk[2 * kk + 1][1], srcB);
                union { unsigned int u[4]; bf16x8 v; } pf;
                pf.u[0] = sel ? b0 : a0;
                pf.u[1] = sel ? b1 : a1;
                pf.u[2] = sel ? b2 : a2;
                pf.u[3] = sel ? b3 : a3;
                for (int c2 = 0; c2 < 8; c2++) {
                    bf16x8 vv = *(const bf16x8*)(Vl + (c2 * 16 + lr) * 64 +
                                                 (((kk * 4 + hi) ^ (lr & 7)) << 3));
                    o_acc[c2] = __builtin_amdgcn_mfma_f32_16x16x32_bf16(
                        vv, pf.v, o_acc[c2], 0, 0, 0);
                }
            }
        }
        __syncthreads();   // drains prefetch vmcnt + syncs buffer flip
        cur ^= 1;
    }

    // epilogue: O^T -> O via per-wave bf16 LDS scratch (SMEM free after loop;
    // all cross-lane traffic is within-wave, no barrier needed).
    unsigned short* scr = SMEM + w * 2176;   // 16 rows x 136 bf16
    float invl = 1.0f / l_r;
    for (int c2 = 0; c2 < 8; c2++) {
        us4 o;
        o.x = f2bf(o_acc[c2][0] * invl); o.y = f2bf(o_acc[c2][1] * invl);
        o.z = f2bf(o_acc[c2][2] * invl); o.w = f2bf(o_acc[c2][3] * invl);
        *(us4*)(scr + lr * 136 + c2 * 16 + hi * 4) = o;
    }
    for (int j = 0; j < 4; j++) {
        bf16x8 v = *(const bf16x8*)(scr + lr * 136 + hi * 32 + j * 8);
        *(bf16x8*)(O + (size_t)qg * HID + h * HD + hi * 32 + j * 8) = v;
    }
}

// ---------------------------------------------------------------------------
extern "C" void kernel_launch(void* const* d_in, const int* in_sizes, int n_in,
                              void* d_out, int out_size, void* d_ws, size_t ws_size,
                              hipStream_t stream) {
    const float* x  = (const float*)d_in[0];
    const float* Wq = (const float*)d_in[1];
    const float* bq = (const float*)d_in[2];
    const float* Wk = (const float*)d_in[3];
    const float* bk = (const float*)d_in[4];
    const float* Wv = (const float*)d_in[5];
    const float* bv = (const float*)d_in[6];
    const float* Wo = (const float*)d_in[7];

    char* ws = (char*)d_ws;
    const size_t MB = 1024 * 1024;
    unsigned short* xb    = (unsigned short*)(ws + 0 * MB);
    unsigned short* WTall = (unsigned short*)(ws + 16 * MB);   // 4 x 8 MB
    unsigned short* Qb    = (unsigned short*)(ws + 48 * MB);
    unsigned short* Kbuf  = (unsigned short*)(ws + 64 * MB);
    unsigned short* VTb   = (unsigned short*)(ws + 80 * MB);
    unsigned short* Ctx   = (unsigned short*)(ws + 96 * MB);

    // 1. x -> bf16
    cvt_f32_bf16<<<8192, 256, 0, stream>>>(x, xb, SQ * HID);
    // 2. all 4 weights -> transposed bf16 (one dispatch)
    transcvt4<<<dim3(HID / 64, HID / 64, 4), 256, 0, stream>>>(Wq, Wk, Wv, Wo, WTall);
    // 3. fused QKV projections (one dispatch)
    gemm_qkv<<<dim3(SQ / 128, 48), 256, 0, stream>>>(xb, WTall, bq, bk, bv,
                                                     Qb, Kbuf, VTb);
    // 4. causal attention
    attn<<<dim3(NH, 32), 512, 0, stream>>>(Qb, Kbuf, VTb, Ctx);
    // 5. output projection (fp32 out, no bias)
    gemm_out<<<dim3(SQ / 128, HID / 128), 256, 0, stream>>>(
        Ctx, WTall + (size_t)3 * HID * HID, (float*)d_out);
}

// Round 7
// 340.209 us; speedup vs baseline: 1.1950x; 1.0434x over previous
//
#include <hip/hip_runtime.h>
#include <hip/hip_bf16.h>
#include <stdint.h>

// Problem: B=1, S=4096, HIDDEN=2048, HEADS=16, HEAD_DIM=128, causal MHA.
// All inputs fp32; output fp32. Compute in bf16 MFMA with fp32 accum.
//
// Workspace layout (bytes), total ~112 MB:
//   xb    [4096][2048] bf16 @ 0         (16 MB)
//   WTall [4][2048][2048] bf16 @ 16 MB  (32 MB: WqT,WkT,WvT,WoT transposed [out][in])
//   Qb    [4096][2048] bf16 @ 48 MB
//   Kb    [4096][2048] bf16 @ 64 MB
//   VTb   [2048][4096] bf16 @ 80 MB     (V transposed per-head: row h*128+d, col s)
//   Ctx   [4096][2048] bf16 @ 96 MB

#define SQ 4096
#define HID 2048
#define NH 16
#define HD 128

typedef __attribute__((ext_vector_type(8))) short bf16x8;
typedef __attribute__((ext_vector_type(4))) float f32x4;
typedef __attribute__((ext_vector_type(4))) unsigned short us4;

__device__ inline unsigned short f2bf(float f) {
    unsigned int u = __builtin_bit_cast(unsigned int, f);
    u = (u + 0x7FFFu + ((u >> 16) & 1u)) >> 16;
    return (unsigned short)u;
}

__device__ inline void gl2lds16(const void* g, void* l) {
    __builtin_amdgcn_global_load_lds(
        (const __attribute__((address_space(1))) unsigned int*)g,
        (__attribute__((address_space(3))) unsigned int*)l, 16, 0, 0);
}

// ---------------- fp32 -> bf16 convert (grid-stride, float4) ----------------
__global__ void cvt_f32_bf16(const float* __restrict__ src,
                             unsigned short* __restrict__ dst, int n) {
    int i = (blockIdx.x * blockDim.x + threadIdx.x) * 4;
    int stride = gridDim.x * blockDim.x * 4;
    for (; i < n; i += stride) {
        float4 v = *(const float4*)(src + i);
        us4 o;
        o.x = f2bf(v.x); o.y = f2bf(v.y); o.z = f2bf(v.z); o.w = f2bf(v.w);
        *(us4*)(dst + i) = o;
    }
}

// ---- transpose + convert all 4 weights: W [K][N] f32 -> WT [N][K] bf16 -----
__global__ void transcvt4(const float* __restrict__ W0, const float* __restrict__ W1,
                          const float* __restrict__ W2, const float* __restrict__ W3,
                          unsigned short* __restrict__ WTall) {
    __shared__ float tile[64][65];
    const float* W = (blockIdx.z == 0) ? W0 : (blockIdx.z == 1) ? W1
                   : (blockIdx.z == 2) ? W2 : W3;
    unsigned short* WT = WTall + (size_t)blockIdx.z * HID * HID;
    int n0 = blockIdx.x * 64, k0 = blockIdx.y * 64;
    int t = threadIdx.x;
    for (int i = 0; i < 4; i++) {
        int idx = i * 256 + t;          // 0..1023
        int k = idx >> 4;               // 64 rows, 16 float4 per row
        int n4 = (idx & 15) << 2;
        float4 v = *(const float4*)(W + (size_t)(k0 + k) * HID + n0 + n4);
        tile[k][n4 + 0] = v.x; tile[k][n4 + 1] = v.y;
        tile[k][n4 + 2] = v.z; tile[k][n4 + 3] = v.w;
    }
    __syncthreads();
    for (int i = 0; i < 4; i++) {
        int idx = i * 256 + t;
        int n = idx >> 4;
        int k4 = (idx & 15) << 2;
        us4 o;
        o.x = f2bf(tile[k4 + 0][n]); o.y = f2bf(tile[k4 + 1][n]);
        o.z = f2bf(tile[k4 + 2][n]); o.w = f2bf(tile[k4 + 3][n]);
        *(us4*)(WT + (size_t)(n0 + n) * HID + k0 + k4) = o;
    }
}

// ---------------- pipelined bf16 GEMM (depth-2 prefetch, 3 LDS buffers) -----
// BM=128, BN=256, BK=64, 512 thr = 8 waves (2m x 4n), wave tile 64x64.
// Tile t -> buf t%3. Per iter: vmcnt(6) [tile t landed, t+1's 6 in flight] ->
// raw s_barrier -> stage tile t+2 into buf (t+2)%3 (= buf of t-1, all waves
// done reading it: they passed the barrier) -> swizzled ds_read + MFMA.
// Never drains vmcnt to 0 in steady state (T4). LDS slot^(row&7) swizzle,
// both-sides (pre-swizzled global source). setprio around MFMA clusters (T5).
// OUTKIND 0: fused QKV (proj = by>>3; Q/K bf16 [M][N]+bias, V bf16 [N][M]+bias)
// OUTKIND 1: f32 out [M][N], no bias (proj=3 -> Wo).
template <int OUTKIND>
__global__ __launch_bounds__(512) void gemm_pipe(
    const unsigned short* __restrict__ A, const unsigned short* __restrict__ WTall,
    const float* __restrict__ bq, const float* __restrict__ bk,
    const float* __restrict__ bv, unsigned short* __restrict__ Qb,
    unsigned short* __restrict__ Kb, unsigned short* __restrict__ VTb,
    float* __restrict__ Cf) {
    const int K = 2048, NT = 32, M = 4096, N = 2048;
    __shared__ __align__(16) unsigned short AL[3][128 * 64];
    __shared__ __align__(16) unsigned short BL[3][256 * 64];
    int m0 = blockIdx.x * 128;
    int proj = (OUTKIND == 0) ? ((int)blockIdx.y >> 3) : 3;
    int n0 = (OUTKIND == 0) ? ((int)blockIdx.y & 7) * 256 : (int)blockIdx.y * 256;
    const unsigned short* BT = WTall + (size_t)proj * HID * HID;
    int t = threadIdx.x, lane = t & 63, w = t >> 6;
    int lr = lane & 15, hi = lane >> 4;
    int wm = w >> 2, wn = w & 3;

    // stage tile (k0) into buf: linear LDS dest, inverse-swizzled global src.
    auto stage = [&](int buf, int k0) {
#pragma unroll
        for (int i = 0; i < 2; i++) {
            int idx = i * 512 + t, r = idx >> 3, s = idx & 7;
            gl2lds16(A + (size_t)(m0 + r) * K + k0 + ((s ^ (r & 7)) << 3),
                     (void*)(&AL[buf][(i * 512 + w * 64) << 3]));
        }
#pragma unroll
        for (int i = 0; i < 4; i++) {
            int idx = i * 512 + t, r = idx >> 3, s = idx & 7;
            gl2lds16(BT + (size_t)(n0 + r) * K + k0 + ((s ^ (r & 7)) << 3),
                     (void*)(&BL[buf][(i * 512 + w * 64) << 3]));
        }
    };

    f32x4 acc[4][4] = {};
    stage(0, 0);
    stage(1, 64);

    for (int tt = 0; tt < NT; ++tt) {
        int c = tt % 3;
        if (tt < NT - 1) asm volatile("s_waitcnt vmcnt(6)" ::: "memory");
        else             asm volatile("s_waitcnt vmcnt(0)" ::: "memory");
        __builtin_amdgcn_s_barrier();
        __builtin_amdgcn_sched_barrier(0);
        if (tt + 2 < NT) stage((tt + 2) % 3, (tt + 2) * 64);
        const unsigned short* Al = &AL[c][0];
        const unsigned short* Bl = &BL[c][0];
#pragma unroll
        for (int kk = 0; kk < 2; ++kk) {
            int sl = ((kk * 4 + hi) ^ (lr & 7)) << 3;   // swizzled 16B slot
            bf16x8 af[4];
#pragma unroll
            for (int mf = 0; mf < 4; ++mf)
                af[mf] = *(const bf16x8*)(Al + (wm * 64 + mf * 16 + lr) * 64 + sl);
#pragma unroll
            for (int nh = 0; nh < 2; ++nh) {
                bf16x8 b0 = *(const bf16x8*)(Bl + (wn * 64 + (nh * 2) * 16 + lr) * 64 + sl);
                bf16x8 b1 = *(const bf16x8*)(Bl + (wn * 64 + (nh * 2 + 1) * 16 + lr) * 64 + sl);
                __builtin_amdgcn_s_setprio(1);
#pragma unroll
                for (int mf = 0; mf < 4; ++mf) {
                    acc[mf][nh * 2] = __builtin_amdgcn_mfma_f32_16x16x32_bf16(
                        af[mf], b0, acc[mf][nh * 2], 0, 0, 0);
                    acc[mf][nh * 2 + 1] = __builtin_amdgcn_mfma_f32_16x16x32_bf16(
                        af[mf], b1, acc[mf][nh * 2 + 1], 0, 0, 0);
                }
                __builtin_amdgcn_s_setprio(0);
            }
        }
    }

    int rbase = hi << 2;
    if (OUTKIND == 0) {
        const float* bias = (proj == 0) ? bq : (proj == 1) ? bk : bv;
        for (int mf = 0; mf < 4; mf++) {
            for (int nf = 0; nf < 4; nf++) {
                int n_g = n0 + wn * 64 + nf * 16 + lr;
                int m_base = m0 + wm * 64 + mf * 16 + rbase;
                float b = bias[n_g];
                if (proj < 2) {
                    unsigned short* Cb = proj ? Kb : Qb;
                    for (int r = 0; r < 4; r++)
                        Cb[(size_t)(m_base + r) * N + n_g] = f2bf(acc[mf][nf][r] + b);
                } else {
                    us4 o;
                    o.x = f2bf(acc[mf][nf][0] + b); o.y = f2bf(acc[mf][nf][1] + b);
                    o.z = f2bf(acc[mf][nf][2] + b); o.w = f2bf(acc[mf][nf][3] + b);
                    *(us4*)(VTb + (size_t)n_g * M + m_base) = o;
                }
            }
        }
    } else {
        for (int mf = 0; mf < 4; mf++)
            for (int nf = 0; nf < 4; nf++) {
                int n_g = n0 + wn * 64 + nf * 16 + lr;
                int m_base = m0 + wm * 64 + mf * 16 + rbase;
                for (int r = 0; r < 4; r++)
                    Cf[(size_t)(m_base + r) * N + n_g] = acc[mf][nf][r];
            }
    }
}

// ---------------- causal flash attention (v6, unchanged) ---------------------
// grid (NH, 32); 512 thr = 8 waves; QBLK=128. strip = 31 - by (heavy first).
// 64 KB LDS -> 2 blocks/CU. head h -> XCD h%8 (L2-shared KV). Swapped math:
// S^T = mfma(K,Q); in-lane softmax; P in registers (cvt_pk + shfl);
// O^T += V^T @ P^T; T13 defer-max; bf16 LDS scratch transpose epilogue.
__global__ __launch_bounds__(512) void attn(
    const unsigned short* __restrict__ Q, const unsigned short* __restrict__ Kc,
    const unsigned short* __restrict__ VT, unsigned short* __restrict__ O) {
    __shared__ __align__(16) unsigned short SMEM[32768];   // 64 KB
    unsigned short* KB = SMEM;              // [2][64*128]
    unsigned short* VB = SMEM + 16384;      // [2][128*64]
    int h = blockIdx.x;
    int strip = 31 - (int)blockIdx.y;       // heavy first
    int t = threadIdx.x, lane = t & 63, w = t >> 6;
    int lr = lane & 15, hi = lane >> 4;
    const float scale = 0.08838834764831845f;  // 1/sqrt(128)

    auto stage = [&](int buf, int kv0) {
        for (int i = 0; i < 2; i++) {
            int idx = i * 512 + t;            // 0..1023
            int r = idx >> 4, s = idx & 15;   // K: 64 rows x 16 slots
            gl2lds16(Kc + (size_t)(kv0 + r) * HID + h * HD + ((s ^ (r & 7)) << 3),
                     (void*)(KB + buf * 8192 + ((i * 512 + w * 64) << 3)));
            int r2 = idx >> 3, s2 = idx & 7;  // VT: 128 rows x 8 slots
            gl2lds16(VT + (size_t)(h * HD + r2) * SQ + kv0 + ((s2 ^ (r2 & 7)) << 3),
                     (void*)(VB + buf * 8192 + ((i * 512 + w * 64) << 3)));
        }
    };

    int qbase = strip * 128;
    int wq0 = qbase + w * 16;
    int qg = wq0 + lr;                 // this lane's q row

    stage(0, 0);
    bf16x8 qf[4];
    for (int ks = 0; ks < 4; ks++)
        qf[ks] = *(const bf16x8*)(Q + (size_t)qg * HID + h * HD + ks * 32 + (hi << 3));
    f32x4 o_acc[8] = {};               // O^T frags: d=16c2+4hi+reg, q=lane&15
    float m_r = -1e30f, l_r = 0.f;
    __syncthreads();

    int nt = 2 * strip + 2;            // KV tiles covering q rows of this strip
    int cur = 0;
    for (int tile = 0; tile < nt; tile++) {
        int kv0 = tile * 64;
        if (tile + 1 < nt) stage(cur ^ 1, kv0 + 64);   // async prefetch
        const unsigned short* Kl = KB + cur * 8192;
        const unsigned short* Vl = VB + cur * 8192;

        if (kv0 <= wq0 + 15) {   // not fully above this wave's diagonal
            f32x4 sfr[4];
            for (int c = 0; c < 4; c++) {
                f32x4 s = {0.f, 0.f, 0.f, 0.f};
                for (int ks = 0; ks < 4; ks++) {
                    bf16x8 kf = *(const bf16x8*)(Kl + (c * 16 + lr) * 128 +
                                                 (((ks * 4 + hi) ^ (lr & 7)) << 3));
                    s = __builtin_amdgcn_mfma_f32_16x16x32_bf16(kf, qf[ks], s, 0, 0, 0);
                }
                sfr[c] = s;
            }
            if (kv0 + 63 > wq0) {
                for (int c = 0; c < 4; c++) {
                    int kgb = kv0 + c * 16 + 4 * hi;
                    for (int r = 0; r < 4; r++) {
                        float v = sfr[c][r] * scale;
                        sfr[c][r] = (kgb + r <= qg) ? v : -1e30f;
                    }
                }
            } else {
                for (int c = 0; c < 4; c++)
                    for (int r = 0; r < 4; r++) sfr[c][r] *= scale;
            }
            float mx = fmaxf(fmaxf(fmaxf(sfr[0][0], sfr[0][1]), fmaxf(sfr[0][2], sfr[0][3])),
                             fmaxf(fmaxf(sfr[1][0], sfr[1][1]), fmaxf(sfr[1][2], sfr[1][3])));
            float mx2 = fmaxf(fmaxf(fmaxf(sfr[2][0], sfr[2][1]), fmaxf(sfr[2][2], sfr[2][3])),
                              fmaxf(fmaxf(sfr[3][0], sfr[3][1]), fmaxf(sfr[3][2], sfr[3][3])));
            mx = fmaxf(mx, mx2);
            mx = fmaxf(mx, __shfl_xor(mx, 16));
            mx = fmaxf(mx, __shfl_xor(mx, 32));
            if (__all((mx - m_r) <= 8.0f)) {
                float rs = 0.f;
                for (int c = 0; c < 4; c++)
                    for (int r = 0; r < 4; r++) {
                        float p = __expf(sfr[c][r] - m_r);
                        sfr[c][r] = p;
                        rs += p;
                    }
                rs += __shfl_xor(rs, 16);
                rs += __shfl_xor(rs, 32);
                l_r += rs;
            } else {
                float mn = fmaxf(m_r, mx);
                float alpha = __expf(m_r - mn);
                m_r = mn;
                float rs = 0.f;
                for (int c = 0; c < 4; c++)
                    for (int r = 0; r < 4; r++) {
                        float p = __expf(sfr[c][r] - mn);
                        sfr[c][r] = p;
                        rs += p;
                    }
                rs += __shfl_xor(rs, 16);
                rs += __shfl_xor(rs, 32);
                l_r = l_r * alpha + rs;
                for (int c2 = 0; c2 < 8; c2++)
                    for (int r = 0; r < 4; r++) o_acc[c2][r] *= alpha;
            }

            unsigned int wpk[4][2];
#pragma unroll
            for (int c = 0; c < 4; c++)
#pragma unroll
                for (int i = 0; i < 2; i++) {
                    unsigned int d;
                    asm("v_cvt_pk_bf16_f32 %0, %1, %2"
                        : "=v"(d) : "v"(sfr[c][2 * i]), "v"(sfr[c][2 * i + 1]));
                    wpk[c][i] = d;
                }
            int srcA = lr + ((hi & 1) << 5);
            int srcB = srcA + 16;
            bool sel = (hi & 2);
#pragma unroll
            for (int kk = 0; kk < 2; kk++) {
                unsigned int a0 = __shfl(wpk[2 * kk][0], srcA);
                unsigned int a1 = __shfl(wpk[2 * kk][1], srcA);
                unsigned int a2 = __shfl(wpk[2 * kk][0], srcB);
                unsigned int a3 = __shfl(wpk[2 * kk][1], srcB);
                unsigned int b0 = __shfl(wpk[2 * kk + 1][0], srcA);
                unsigned int b1 = __shfl(wpk[2 * kk + 1][1], srcA);
                unsigned int b2 = __shfl(wpk[2 * kk + 1][0], srcB);
                unsigned int b3 = __shfl(wpk[2 * kk + 1][1], srcB);
                union { unsigned int u[4]; bf16x8 v; } pf;
                pf.u[0] = sel ? b0 : a0;
                pf.u[1] = sel ? b1 : a1;
                pf.u[2] = sel ? b2 : a2;
                pf.u[3] = sel ? b3 : a3;
                for (int c2 = 0; c2 < 8; c2++) {
                    bf16x8 vv = *(const bf16x8*)(Vl + (c2 * 16 + lr) * 64 +
                                                 (((kk * 4 + hi) ^ (lr & 7)) << 3));
                    o_acc[c2] = __builtin_amdgcn_mfma_f32_16x16x32_bf16(
                        vv, pf.v, o_acc[c2], 0, 0, 0);
                }
            }
        }
        __syncthreads();   // drains prefetch vmcnt + syncs buffer flip
        cur ^= 1;
    }

    unsigned short* scr = SMEM + w * 2176;   // 16 rows x 136 bf16
    float invl = 1.0f / l_r;
    for (int c2 = 0; c2 < 8; c2++) {
        us4 o;
        o.x = f2bf(o_acc[c2][0] * invl); o.y = f2bf(o_acc[c2][1] * invl);
        o.z = f2bf(o_acc[c2][2] * invl); o.w = f2bf(o_acc[c2][3] * invl);
        *(us4*)(scr + lr * 136 + c2 * 16 + hi * 4) = o;
    }
    for (int j = 0; j < 4; j++) {
        bf16x8 v = *(const bf16x8*)(scr + lr * 136 + hi * 32 + j * 8);
        *(bf16x8*)(O + (size_t)qg * HID + h * HD + hi * 32 + j * 8) = v;
    }
}

// ---------------------------------------------------------------------------
extern "C" void kernel_launch(void* const* d_in, const int* in_sizes, int n_in,
                              void* d_out, int out_size, void* d_ws, size_t ws_size,
                              hipStream_t stream) {
    const float* x  = (const float*)d_in[0];
    const float* Wq = (const float*)d_in[1];
    const float* bq = (const float*)d_in[2];
    const float* Wk = (const float*)d_in[3];
    const float* bk = (const float*)d_in[4];
    const float* Wv = (const float*)d_in[5];
    const float* bv = (const float*)d_in[6];
    const float* Wo = (const float*)d_in[7];

    char* ws = (char*)d_ws;
    const size_t MB = 1024 * 1024;
    unsigned short* xb    = (unsigned short*)(ws + 0 * MB);
    unsigned short* WTall = (unsigned short*)(ws + 16 * MB);   // 4 x 8 MB
    unsigned short* Qb    = (unsigned short*)(ws + 48 * MB);
    unsigned short* Kbuf  = (unsigned short*)(ws + 64 * MB);
    unsigned short* VTb   = (unsigned short*)(ws + 80 * MB);
    unsigned short* Ctx   = (unsigned short*)(ws + 96 * MB);

    // 1. x -> bf16
    cvt_f32_bf16<<<8192, 256, 0, stream>>>(x, xb, SQ * HID);
    // 2. all 4 weights -> transposed bf16 (one dispatch)
    transcvt4<<<dim3(HID / 64, HID / 64, 4), 256, 0, stream>>>(Wq, Wk, Wv, Wo, WTall);
    // 3. fused QKV projections (pipelined GEMM, 768 blocks = 3 exact rounds)
    gemm_pipe<0><<<dim3(32, 24), 512, 0, stream>>>(xb, WTall, bq, bk, bv,
                                                   Qb, Kbuf, VTb, nullptr);
    // 4. causal attention
    attn<<<dim3(NH, 32), 512, 0, stream>>>(Qb, Kbuf, VTb, Ctx);
    // 5. output projection (pipelined GEMM, 256 blocks = 1/CU)
    gemm_pipe<1><<<dim3(32, 8), 512, 0, stream>>>(Ctx, WTall, nullptr, nullptr,
                                                  nullptr, nullptr, nullptr,
                                                  nullptr, (float*)d_out);
}

// Round 8
// 334.616 us; speedup vs baseline: 1.2149x; 1.0167x over previous
//
#include <hip/hip_runtime.h>
#include <hip/hip_bf16.h>
#include <stdint.h>

// Problem: B=1, S=4096, HIDDEN=2048, HEADS=16, HEAD_DIM=128, causal MHA.
// All inputs fp32; output fp32. Compute in bf16 MFMA with fp32 accum.
//
// Workspace layout (bytes), total ~112 MB:
//   xb    [4096][2048] bf16 @ 0         (16 MB)
//   WTall [4][2048][2048] bf16 @ 16 MB  (32 MB: WqT,WkT,WvT,WoT transposed [out][in])
//   Qb    [4096][2048] bf16 @ 48 MB
//   Kb    [4096][2048] bf16 @ 64 MB
//   VTb   [2048][4096] bf16 @ 80 MB     (V transposed per-head: row h*128+d, col s)
//   Ctx   [4096][2048] bf16 @ 96 MB

#define SQ 4096
#define HID 2048
#define NH 16
#define HD 128

typedef __attribute__((ext_vector_type(8))) short bf16x8;
typedef __attribute__((ext_vector_type(4))) float f32x4;
typedef __attribute__((ext_vector_type(4))) unsigned short us4;

__device__ inline unsigned short f2bf(float f) {
    unsigned int u = __builtin_bit_cast(unsigned int, f);
    u = (u + 0x7FFFu + ((u >> 16) & 1u)) >> 16;
    return (unsigned short)u;
}

__device__ inline void gl2lds16(const void* g, void* l) {
    __builtin_amdgcn_global_load_lds(
        (const __attribute__((address_space(1))) unsigned int*)g,
        (__attribute__((address_space(3))) unsigned int*)l, 16, 0, 0);
}

// ---------------- fp32 -> bf16 convert (grid-stride, float4) ----------------
__global__ void cvt_f32_bf16(const float* __restrict__ src,
                             unsigned short* __restrict__ dst, int n) {
    int i = (blockIdx.x * blockDim.x + threadIdx.x) * 4;
    int stride = gridDim.x * blockDim.x * 4;
    for (; i < n; i += stride) {
        float4 v = *(const float4*)(src + i);
        us4 o;
        o.x = f2bf(v.x); o.y = f2bf(v.y); o.z = f2bf(v.z); o.w = f2bf(v.w);
        *(us4*)(dst + i) = o;
    }
}

// ---- transpose + convert all 4 weights: W [K][N] f32 -> WT [N][K] bf16 -----
__global__ void transcvt4(const float* __restrict__ W0, const float* __restrict__ W1,
                          const float* __restrict__ W2, const float* __restrict__ W3,
                          unsigned short* __restrict__ WTall) {
    __shared__ float tile[64][65];
    const float* W = (blockIdx.z == 0) ? W0 : (blockIdx.z == 1) ? W1
                   : (blockIdx.z == 2) ? W2 : W3;
    unsigned short* WT = WTall + (size_t)blockIdx.z * HID * HID;
    int n0 = blockIdx.x * 64, k0 = blockIdx.y * 64;
    int t = threadIdx.x;
    for (int i = 0; i < 4; i++) {
        int idx = i * 256 + t;          // 0..1023
        int k = idx >> 4;               // 64 rows, 16 float4 per row
        int n4 = (idx & 15) << 2;
        float4 v = *(const float4*)(W + (size_t)(k0 + k) * HID + n0 + n4);
        tile[k][n4 + 0] = v.x; tile[k][n4 + 1] = v.y;
        tile[k][n4 + 2] = v.z; tile[k][n4 + 3] = v.w;
    }
    __syncthreads();
    for (int i = 0; i < 4; i++) {
        int idx = i * 256 + t;
        int n = idx >> 4;
        int k4 = (idx & 15) << 2;
        us4 o;
        o.x = f2bf(tile[k4 + 0][n]); o.y = f2bf(tile[k4 + 1][n]);
        o.z = f2bf(tile[k4 + 2][n]); o.w = f2bf(tile[k4 + 3][n]);
        *(us4*)(WT + (size_t)(n0 + n) * HID + k0 + k4) = o;
    }
}

// ---------------- pipelined bf16 GEMM (depth-2 prefetch, 3 LDS buffers) -----
// BM=128, BN=256, BK=64, 512 thr = 8 waves (2m x 4n), wave tile 64x64.
// Tile t -> buf t%3. Per iter: vmcnt(6) -> raw s_barrier -> stage tile t+2 ->
// swizzled ds_read + MFMA. Never drains vmcnt to 0 in steady state (T4).
// LDS slot^(row&7) swizzle both-sides. setprio around MFMA clusters (T5).
// OUTKIND 0: fused QKV (proj = by>>3; Q/K bf16 [M][N]+bias, V bf16 [N][M]+bias)
// OUTKIND 1: f32 out [M][N], no bias (proj=3 -> Wo).
template <int OUTKIND>
__global__ __launch_bounds__(512) void gemm_pipe(
    const unsigned short* __restrict__ A, const unsigned short* __restrict__ WTall,
    const float* __restrict__ bq, const float* __restrict__ bk,
    const float* __restrict__ bv, unsigned short* __restrict__ Qb,
    unsigned short* __restrict__ Kb, unsigned short* __restrict__ VTb,
    float* __restrict__ Cf) {
    const int K = 2048, NT = 32, M = 4096, N = 2048;
    __shared__ __align__(16) unsigned short AL[3][128 * 64];
    __shared__ __align__(16) unsigned short BL[3][256 * 64];
    int m0 = blockIdx.x * 128;
    int proj = (OUTKIND == 0) ? ((int)blockIdx.y >> 3) : 3;
    int n0 = (OUTKIND == 0) ? ((int)blockIdx.y & 7) * 256 : (int)blockIdx.y * 256;
    const unsigned short* BT = WTall + (size_t)proj * HID * HID;
    int t = threadIdx.x, lane = t & 63, w = t >> 6;
    int lr = lane & 15, hi = lane >> 4;
    int wm = w >> 2, wn = w & 3;

    auto stage = [&](int buf, int k0) {
#pragma unroll
        for (int i = 0; i < 2; i++) {
            int idx = i * 512 + t, r = idx >> 3, s = idx & 7;
            gl2lds16(A + (size_t)(m0 + r) * K + k0 + ((s ^ (r & 7)) << 3),
                     (void*)(&AL[buf][(i * 512 + w * 64) << 3]));
        }
#pragma unroll
        for (int i = 0; i < 4; i++) {
            int idx = i * 512 + t, r = idx >> 3, s = idx & 7;
            gl2lds16(BT + (size_t)(n0 + r) * K + k0 + ((s ^ (r & 7)) << 3),
                     (void*)(&BL[buf][(i * 512 + w * 64) << 3]));
        }
    };

    f32x4 acc[4][4] = {};
    stage(0, 0);
    stage(1, 64);

    for (int tt = 0; tt < NT; ++tt) {
        int c = tt % 3;
        if (tt < NT - 1) asm volatile("s_waitcnt vmcnt(6)" ::: "memory");
        else             asm volatile("s_waitcnt vmcnt(0)" ::: "memory");
        __builtin_amdgcn_s_barrier();
        __builtin_amdgcn_sched_barrier(0);
        if (tt + 2 < NT) stage((tt + 2) % 3, (tt + 2) * 64);
        const unsigned short* Al = &AL[c][0];
        const unsigned short* Bl = &BL[c][0];
#pragma unroll
        for (int kk = 0; kk < 2; ++kk) {
            int sl = ((kk * 4 + hi) ^ (lr & 7)) << 3;   // swizzled 16B slot
            bf16x8 af[4];
#pragma unroll
            for (int mf = 0; mf < 4; ++mf)
                af[mf] = *(const bf16x8*)(Al + (wm * 64 + mf * 16 + lr) * 64 + sl);
#pragma unroll
            for (int nh = 0; nh < 2; ++nh) {
                bf16x8 b0 = *(const bf16x8*)(Bl + (wn * 64 + (nh * 2) * 16 + lr) * 64 + sl);
                bf16x8 b1 = *(const bf16x8*)(Bl + (wn * 64 + (nh * 2 + 1) * 16 + lr) * 64 + sl);
                __builtin_amdgcn_s_setprio(1);
#pragma unroll
                for (int mf = 0; mf < 4; ++mf) {
                    acc[mf][nh * 2] = __builtin_amdgcn_mfma_f32_16x16x32_bf16(
                        af[mf], b0, acc[mf][nh * 2], 0, 0, 0);
                    acc[mf][nh * 2 + 1] = __builtin_amdgcn_mfma_f32_16x16x32_bf16(
                        af[mf], b1, acc[mf][nh * 2 + 1], 0, 0, 0);
                }
                __builtin_amdgcn_s_setprio(0);
            }
        }
    }

    int rbase = hi << 2;
    if (OUTKIND == 0) {
        const float* bias = (proj == 0) ? bq : (proj == 1) ? bk : bv;
        for (int mf = 0; mf < 4; mf++) {
            for (int nf = 0; nf < 4; nf++) {
                int n_g = n0 + wn * 64 + nf * 16 + lr;
                int m_base = m0 + wm * 64 + mf * 16 + rbase;
                float b = bias[n_g];
                if (proj < 2) {
                    unsigned short* Cb = proj ? Kb : Qb;
                    for (int r = 0; r < 4; r++)
                        Cb[(size_t)(m_base + r) * N + n_g] = f2bf(acc[mf][nf][r] + b);
                } else {
                    us4 o;
                    o.x = f2bf(acc[mf][nf][0] + b); o.y = f2bf(acc[mf][nf][1] + b);
                    o.z = f2bf(acc[mf][nf][2] + b); o.w = f2bf(acc[mf][nf][3] + b);
                    *(us4*)(VTb + (size_t)n_g * M + m_base) = o;
                }
            }
        }
    } else {
        for (int mf = 0; mf < 4; mf++)
            for (int nf = 0; nf < 4; nf++) {
                int n_g = n0 + wn * 64 + nf * 16 + lr;
                int m_base = m0 + wm * 64 + mf * 16 + rbase;
                for (int r = 0; r < 4; r++)
                    Cf[(size_t)(m_base + r) * N + n_g] = acc[mf][nf][r];
            }
    }
}

// ---------------- causal flash attention (v7: KVBLK=128, balanced pairs) -----
// grid (NH, 16); 512 thr = 8 waves; QBLK=128. Block (h, by) processes strips
// {by, 31-by} sequentially -> exactly 33 KV-tiles (KVBLK=128) per block: all
// 256 blocks identical, 1/CU, zero tail. 128 KB LDS (dbuf K[128x128] +
// VT[128x128]). Doubled tile halves barrier count per unit work; depth-1
// prefetch hides under ~2x compute. Swapped math (S^T = mfma(K,Q)), in-lane
// softmax, in-register P (cvt_pk + shfl), T13 defer-max, LDS-scratch epilogue.
__global__ __launch_bounds__(512) void attn(
    const unsigned short* __restrict__ Q, const unsigned short* __restrict__ Kc,
    const unsigned short* __restrict__ VT, unsigned short* __restrict__ O) {
    __shared__ __align__(16) unsigned short SMEM[65536];   // 128 KB
    unsigned short* KB = SMEM;              // [2][128*128]
    unsigned short* VB = SMEM + 32768;      // [2][128*128]
    int h = blockIdx.x;
    int by = blockIdx.y;
    int t = threadIdx.x, lane = t & 63, w = t >> 6;
    int lr = lane & 15, hi = lane >> 4;
    const float scale = 0.08838834764831845f;  // 1/sqrt(128)

    // stage K/V tile [kv0, kv0+128) into buffer `buf` (32 KB each of K, VT).
    // Linear LDS dest, inverse-swizzled global source (slot ^ (row&7)).
    auto stage = [&](int buf, int kv0) {
#pragma unroll
        for (int i = 0; i < 4; i++) {
            int idx = i * 512 + t;            // 0..2047
            int r = idx >> 4, s = idx & 15;   // K: 128 rows x 16 slots
            gl2lds16(Kc + (size_t)(kv0 + r) * HID + h * HD + ((s ^ (r & 7)) << 3),
                     (void*)(KB + buf * 16384 + ((i * 512 + w * 64) << 3)));
        }
#pragma unroll
        for (int i = 0; i < 4; i++) {
            int idx = i * 512 + t;
            int r = idx >> 4, s = idx & 15;   // VT: 128 rows x 16 slots
            gl2lds16(VT + (size_t)(h * HD + r) * SQ + kv0 + ((s ^ (r & 7)) << 3),
                     (void*)(VB + buf * 16384 + ((i * 512 + w * 64) << 3)));
        }
    };

    int strips[2] = {31 - by, by};
    for (int sp = 0; sp < 2; sp++) {
        int strip = strips[sp];
        int qbase = strip * 128;
        int wq0 = qbase + w * 16;
        int qg = wq0 + lr;                 // this lane's q row

        stage(0, 0);
        bf16x8 qf[4];
        for (int ks = 0; ks < 4; ks++)
            qf[ks] = *(const bf16x8*)(Q + (size_t)qg * HID + h * HD + ks * 32 + (hi << 3));
        f32x4 o_acc[8] = {};               // O^T frags: d=16c2+4hi+reg, q=lane&15
        float m_r = -1e30f, l_r = 0.f;
        __syncthreads();

        int nt = strip + 1;                // 128-wide KV tiles for this strip
        int cur = 0;
        for (int tile = 0; tile < nt; tile++) {
            int kv0 = tile * 128;
            if (tile + 1 < nt) stage(cur ^ 1, kv0 + 128);   // async prefetch
            const unsigned short* Kl = KB + cur * 16384;
            const unsigned short* Vl = VB + cur * 16384;

            if (kv0 <= wq0 + 15) {   // not fully above this wave's diagonal
                // S^T = mfma(K, Q): sfr[c][r] = S^T[k=16c+4hi+r][q=lane&15]
                f32x4 sfr[8];
#pragma unroll
                for (int c = 0; c < 8; c++) {
                    f32x4 s = {0.f, 0.f, 0.f, 0.f};
#pragma unroll
                    for (int ks = 0; ks < 4; ks++) {
                        bf16x8 kf = *(const bf16x8*)(Kl + (c * 16 + lr) * 128 +
                                                     (((ks * 4 + hi) ^ (lr & 7)) << 3));
                        s = __builtin_amdgcn_mfma_f32_16x16x32_bf16(kf, qf[ks], s, 0, 0, 0);
                    }
                    sfr[c] = s;
                }
                // scale + causal mask (k_g <= q_g)
                if (kv0 + 127 > wq0) {
#pragma unroll
                    for (int c = 0; c < 8; c++) {
                        int kgb = kv0 + c * 16 + 4 * hi;
                        for (int r = 0; r < 4; r++) {
                            float v = sfr[c][r] * scale;
                            sfr[c][r] = (kgb + r <= qg) ? v : -1e30f;
                        }
                    }
                } else {
#pragma unroll
                    for (int c = 0; c < 8; c++)
                        for (int r = 0; r < 4; r++) sfr[c][r] *= scale;
                }
                // in-lane row max (32 values) + cross-hi (2 shfl_xor)
                float mx = -1e30f;
#pragma unroll
                for (int c = 0; c < 8; c++)
                    mx = fmaxf(mx, fmaxf(fmaxf(sfr[c][0], sfr[c][1]),
                                         fmaxf(sfr[c][2], sfr[c][3])));
                mx = fmaxf(mx, __shfl_xor(mx, 16));
                mx = fmaxf(mx, __shfl_xor(mx, 32));
                // T13 defer-max
                if (__all((mx - m_r) <= 8.0f)) {
                    float rs = 0.f;
#pragma unroll
                    for (int c = 0; c < 8; c++)
                        for (int r = 0; r < 4; r++) {
                            float p = __expf(sfr[c][r] - m_r);
                            sfr[c][r] = p;
                            rs += p;
                        }
                    rs += __shfl_xor(rs, 16);
                    rs += __shfl_xor(rs, 32);
                    l_r += rs;
                } else {
                    float mn = fmaxf(m_r, mx);
                    float alpha = __expf(m_r - mn);
                    m_r = mn;
                    float rs = 0.f;
#pragma unroll
                    for (int c = 0; c < 8; c++)
                        for (int r = 0; r < 4; r++) {
                            float p = __expf(sfr[c][r] - mn);
                            sfr[c][r] = p;
                            rs += p;
                        }
                    rs += __shfl_xor(rs, 16);
                    rs += __shfl_xor(rs, 32);
                    l_r = l_r * alpha + rs;
                    for (int c2 = 0; c2 < 8; c2++)
                        for (int r = 0; r < 4; r++) o_acc[c2][r] *= alpha;
                }

                // P^T -> PV B-operand fragments, fully in-register.
                unsigned int wpk[8][2];
#pragma unroll
                for (int c = 0; c < 8; c++)
#pragma unroll
                    for (int i = 0; i < 2; i++) {
                        unsigned int d;
                        asm("v_cvt_pk_bf16_f32 %0, %1, %2"
                            : "=v"(d) : "v"(sfr[c][2 * i]), "v"(sfr[c][2 * i + 1]));
                        wpk[c][i] = d;
                    }
                int srcA = lr + ((hi & 1) << 5);
                int srcB = srcA + 16;
                bool sel = (hi & 2);
#pragma unroll
                for (int kk = 0; kk < 4; kk++) {
                    unsigned int a0 = __shfl(wpk[2 * kk][0], srcA);
                    unsigned int a1 = __shfl(wpk[2 * kk][1], srcA);
                    unsigned int a2 = __shfl(wpk[2 * kk][0], srcB);
                    unsigned int a3 = __shfl(wpk[2 * kk][1], srcB);
                    unsigned int b0 = __shfl(wpk[2 * kk + 1][0], srcA);
                    unsigned int b1 = __shfl(wpk[2 * kk + 1][1], srcA);
                    unsigned int b2 = __shfl(wpk[2 * kk + 1][0], srcB);
                    unsigned int b3 = __shfl(wpk[2 * kk + 1][1], srcB);
                    union { unsigned int u[4]; bf16x8 v; } pf;
                    pf.u[0] = sel ? b0 : a0;
                    pf.u[1] = sel ? b1 : a1;
                    pf.u[2] = sel ? b2 : a2;
                    pf.u[3] = sel ? b3 : a3;
                    // O^T += V^T @ P^T : A = V^T (rows d), B = P^T frag
#pragma unroll
                    for (int c2 = 0; c2 < 8; c2++) {
                        bf16x8 vv = *(const bf16x8*)(Vl + (c2 * 16 + lr) * 128 +
                                                     (((kk * 4 + hi) ^ (lr & 7)) << 3));
                        o_acc[c2] = __builtin_amdgcn_mfma_f32_16x16x32_bf16(
                            vv, pf.v, o_acc[c2], 0, 0, 0);
                    }
                }
            }
            __syncthreads();   // drains prefetch vmcnt + syncs buffer flip
            cur ^= 1;
        }

        // epilogue: O^T -> O via per-wave bf16 LDS scratch (within-wave only).
        unsigned short* scr = SMEM + w * 2176;   // 16 rows x 136 bf16
        float invl = 1.0f / l_r;
        for (int c2 = 0; c2 < 8; c2++) {
            us4 o;
            o.x = f2bf(o_acc[c2][0] * invl); o.y = f2bf(o_acc[c2][1] * invl);
            o.z = f2bf(o_acc[c2][2] * invl); o.w = f2bf(o_acc[c2][3] * invl);
            *(us4*)(scr + lr * 136 + c2 * 16 + hi * 4) = o;
        }
        for (int j = 0; j < 4; j++) {
            bf16x8 v = *(const bf16x8*)(scr + lr * 136 + hi * 32 + j * 8);
            *(bf16x8*)(O + (size_t)qg * HID + h * HD + hi * 32 + j * 8) = v;
        }
        __syncthreads();   // scratch reads done before next strip re-stages
    }
}

// ---------------------------------------------------------------------------
extern "C" void kernel_launch(void* const* d_in, const int* in_sizes, int n_in,
                              void* d_out, int out_size, void* d_ws, size_t ws_size,
                              hipStream_t stream) {
    const float* x  = (const float*)d_in[0];
    const float* Wq = (const float*)d_in[1];
    const float* bq = (const float*)d_in[2];
    const float* Wk = (const float*)d_in[3];
    const float* bk = (const float*)d_in[4];
    const float* Wv = (const float*)d_in[5];
    const float* bv = (const float*)d_in[6];
    const float* Wo = (const float*)d_in[7];

    char* ws = (char*)d_ws;
    const size_t MB = 1024 * 1024;
    unsigned short* xb    = (unsigned short*)(ws + 0 * MB);
    unsigned short* WTall = (unsigned short*)(ws + 16 * MB);   // 4 x 8 MB
    unsigned short* Qb    = (unsigned short*)(ws + 48 * MB);
    unsigned short* Kbuf  = (unsigned short*)(ws + 64 * MB);
    unsigned short* VTb   = (unsigned short*)(ws + 80 * MB);
    unsigned short* Ctx   = (unsigned short*)(ws + 96 * MB);

    // 1. x -> bf16
    cvt_f32_bf16<<<8192, 256, 0, stream>>>(x, xb, SQ * HID);
    // 2. all 4 weights -> transposed bf16 (one dispatch)
    transcvt4<<<dim3(HID / 64, HID / 64, 4), 256, 0, stream>>>(Wq, Wk, Wv, Wo, WTall);
    // 3. fused QKV projections (pipelined GEMM, 768 blocks = 3 exact rounds)
    gemm_pipe<0><<<dim3(32, 24), 512, 0, stream>>>(xb, WTall, bq, bk, bv,
                                                   Qb, Kbuf, VTb, nullptr);
    // 4. causal attention (256 identical blocks, 1/CU)
    attn<<<dim3(NH, 16), 512, 0, stream>>>(Qb, Kbuf, VTb, Ctx);
    // 5. output projection (pipelined GEMM, 256 blocks = 1/CU)
    gemm_pipe<1><<<dim3(32, 8), 512, 0, stream>>>(Ctx, WTall, nullptr, nullptr,
                                                  nullptr, nullptr, nullptr,
                                                  nullptr, (float*)d_out);
}

// Round 9
// 301.502 us; speedup vs baseline: 1.3484x; 1.1098x over previous
//
#include <hip/hip_runtime.h>
#include <hip/hip_bf16.h>
#include <stdint.h>

// Problem: B=1, S=4096, HIDDEN=2048, HEADS=16, HEAD_DIM=128, causal MHA.
// All inputs fp32; output fp32. Compute in bf16 MFMA with fp32 accum.
//
// Workspace layout (bytes), total ~112 MB:
//   xb    [4096][2048] bf16 @ 0         (16 MB)
//   WTall [4][2048][2048] bf16 @ 16 MB  (32 MB: WqT,WkT,WvT,WoT transposed [out][in])
//   Qb    [4096][2048] bf16 @ 48 MB
//   Kb    [4096][2048] bf16 @ 64 MB
//   VTb   [2048][4096] bf16 @ 80 MB     (V transposed per-head: row h*128+d, col s)
//   Ctx   [4096][2048] bf16 @ 96 MB

#define SQ 4096
#define HID 2048
#define NH 16
#define HD 128

typedef __attribute__((ext_vector_type(8))) short bf16x8;
typedef __attribute__((ext_vector_type(4))) float f32x4;
typedef __attribute__((ext_vector_type(4))) unsigned short us4;

__device__ inline unsigned short f2bf(float f) {
    unsigned int u = __builtin_bit_cast(unsigned int, f);
    u = (u + 0x7FFFu + ((u >> 16) & 1u)) >> 16;
    return (unsigned short)u;
}

__device__ inline void gl2lds16(const void* g, void* l) {
    __builtin_amdgcn_global_load_lds(
        (const __attribute__((address_space(1))) unsigned int*)g,
        (__attribute__((address_space(3))) unsigned int*)l, 16, 0, 0);
}

// ---------------- fp32 -> bf16 convert (grid-stride, float4) ----------------
__global__ void cvt_f32_bf16(const float* __restrict__ src,
                             unsigned short* __restrict__ dst, int n) {
    int i = (blockIdx.x * blockDim.x + threadIdx.x) * 4;
    int stride = gridDim.x * blockDim.x * 4;
    for (; i < n; i += stride) {
        float4 v = *(const float4*)(src + i);
        us4 o;
        o.x = f2bf(v.x); o.y = f2bf(v.y); o.z = f2bf(v.z); o.w = f2bf(v.w);
        *(us4*)(dst + i) = o;
    }
}

// ---- transpose + convert all 4 weights: W [K][N] f32 -> WT [N][K] bf16 -----
__global__ void transcvt4(const float* __restrict__ W0, const float* __restrict__ W1,
                          const float* __restrict__ W2, const float* __restrict__ W3,
                          unsigned short* __restrict__ WTall) {
    __shared__ float tile[64][65];
    const float* W = (blockIdx.z == 0) ? W0 : (blockIdx.z == 1) ? W1
                   : (blockIdx.z == 2) ? W2 : W3;
    unsigned short* WT = WTall + (size_t)blockIdx.z * HID * HID;
    int n0 = blockIdx.x * 64, k0 = blockIdx.y * 64;
    int t = threadIdx.x;
    for (int i = 0; i < 4; i++) {
        int idx = i * 256 + t;          // 0..1023
        int k = idx >> 4;               // 64 rows, 16 float4 per row
        int n4 = (idx & 15) << 2;
        float4 v = *(const float4*)(W + (size_t)(k0 + k) * HID + n0 + n4);
        tile[k][n4 + 0] = v.x; tile[k][n4 + 1] = v.y;
        tile[k][n4 + 2] = v.z; tile[k][n4 + 3] = v.w;
    }
    __syncthreads();
    for (int i = 0; i < 4; i++) {
        int idx = i * 256 + t;
        int n = idx >> 4;
        int k4 = (idx & 15) << 2;
        us4 o;
        o.x = f2bf(tile[k4 + 0][n]); o.y = f2bf(tile[k4 + 1][n]);
        o.z = f2bf(tile[k4 + 2][n]); o.w = f2bf(tile[k4 + 3][n]);
        *(us4*)(WT + (size_t)(n0 + n) * HID + k0 + k4) = o;
    }
}

// ---------------- pipelined bf16 GEMM (2 blocks/CU for TLP overlap) ---------
// BM=BN=128, BK=64, 256 thr = 4 waves (2m x 2n), wave tile 64x64.
// 2 LDS buffers (64 KB total) -> 2 blocks/CU: when one block stalls on its
// per-tile vmcnt+barrier, the other block's waves fill the CU (m114 overlap —
// the missing mechanism at 147 KB/1-block). Issue-early/wait-late: tile t+1's
// 6 loads are issued right after the barrier of tile t, so the vmcnt(0) at the
// top of tile t+1 drains loads that had a full K-tile of compute to land.
// Zero-conflict LDS: slot^(row&7) 16B-slot swizzle, both-sides (pre-swizzled
// global source, swizzled ds_read). setprio(1) around MFMA clusters.
// OUTKIND 0: fused QKV (proj = by>>4; Q/K bf16 [M][N]+bias, V bf16 [N][M]+bias)
// OUTKIND 1: f32 out [M][N], no bias (proj=3 -> Wo).
template <int OUTKIND>
__global__ __launch_bounds__(256) void gemm_pipe(
    const unsigned short* __restrict__ A, const unsigned short* __restrict__ WTall,
    const float* __restrict__ bq, const float* __restrict__ bk,
    const float* __restrict__ bv, unsigned short* __restrict__ Qb,
    unsigned short* __restrict__ Kb, unsigned short* __restrict__ VTb,
    float* __restrict__ Cf) {
    const int K = 2048, NT = 32, M = 4096, N = 2048;
    __shared__ __align__(16) unsigned short AL[2][128 * 64];
    __shared__ __align__(16) unsigned short BL[2][128 * 64];
    int m0 = blockIdx.x * 128;
    int proj = (OUTKIND == 0) ? ((int)blockIdx.y >> 4) : 3;
    int n0 = (OUTKIND == 0) ? ((int)blockIdx.y & 15) * 128 : (int)blockIdx.y * 128;
    const unsigned short* BT = WTall + (size_t)proj * HID * HID;
    int t = threadIdx.x, lane = t & 63, w = t >> 6;
    int lr = lane & 15, hi = lane >> 4;
    int wm = w >> 1, wn = w & 1;

    // stage K-tile k0 into buf: linear LDS dest, inverse-swizzled global src.
    auto stage = [&](int buf, int k0) {
#pragma unroll
        for (int i = 0; i < 4; i++) {
            int idx = i * 256 + t, r = idx >> 3, s = idx & 7;
            gl2lds16(A + (size_t)(m0 + r) * K + k0 + ((s ^ (r & 7)) << 3),
                     (void*)(&AL[buf][(i * 256 + w * 64) << 3]));
        }
#pragma unroll
        for (int i = 0; i < 4; i++) {
            int idx = i * 256 + t, r = idx >> 3, s = idx & 7;
            gl2lds16(BT + (size_t)(n0 + r) * K + k0 + ((s ^ (r & 7)) << 3),
                     (void*)(&BL[buf][(i * 256 + w * 64) << 3]));
        }
    };

    f32x4 acc[4][4] = {};
    stage(0, 0);

    for (int tt = 0; tt < NT; ++tt) {
        int c = tt & 1;
        asm volatile("s_waitcnt vmcnt(0)" ::: "memory");  // tile tt landed
        __builtin_amdgcn_s_barrier();                     // all waves see it;
        __builtin_amdgcn_sched_barrier(0);                // buf c^1 free to reuse
        if (tt + 1 < NT) stage(c ^ 1, (tt + 1) * 64);     // issue early
        const unsigned short* Al = &AL[c][0];
        const unsigned short* Bl = &BL[c][0];
#pragma unroll
        for (int kk = 0; kk < 2; ++kk) {
            int sl = ((kk * 4 + hi) ^ (lr & 7)) << 3;   // swizzled 16B slot
            bf16x8 af[4], bfg[4];
#pragma unroll
            for (int mf = 0; mf < 4; ++mf)
                af[mf] = *(const bf16x8*)(Al + (wm * 64 + mf * 16 + lr) * 64 + sl);
#pragma unroll
            for (int nf = 0; nf < 4; ++nf)
                bfg[nf] = *(const bf16x8*)(Bl + (wn * 64 + nf * 16 + lr) * 64 + sl);
            __builtin_amdgcn_s_setprio(1);
#pragma unroll
            for (int mf = 0; mf < 4; ++mf)
#pragma unroll
                for (int nf = 0; nf < 4; ++nf)
                    acc[mf][nf] = __builtin_amdgcn_mfma_f32_16x16x32_bf16(
                        af[mf], bfg[nf], acc[mf][nf], 0, 0, 0);
            __builtin_amdgcn_s_setprio(0);
        }
    }

    int rbase = hi << 2;
    if (OUTKIND == 0) {
        const float* bias = (proj == 0) ? bq : (proj == 1) ? bk : bv;
        for (int mf = 0; mf < 4; mf++) {
            for (int nf = 0; nf < 4; nf++) {
                int n_g = n0 + wn * 64 + nf * 16 + lr;
                int m_base = m0 + wm * 64 + mf * 16 + rbase;
                float b = bias[n_g];
                if (proj < 2) {
                    unsigned short* Cb = proj ? Kb : Qb;
                    for (int r = 0; r < 4; r++)
                        Cb[(size_t)(m_base + r) * N + n_g] = f2bf(acc[mf][nf][r] + b);
                } else {
                    us4 o;
                    o.x = f2bf(acc[mf][nf][0] + b); o.y = f2bf(acc[mf][nf][1] + b);
                    o.z = f2bf(acc[mf][nf][2] + b); o.w = f2bf(acc[mf][nf][3] + b);
                    *(us4*)(VTb + (size_t)n_g * M + m_base) = o;
                }
            }
        }
    } else {
        for (int mf = 0; mf < 4; mf++)
            for (int nf = 0; nf < 4; nf++) {
                int n_g = n0 + wn * 64 + nf * 16 + lr;
                int m_base = m0 + wm * 64 + mf * 16 + rbase;
                for (int r = 0; r < 4; r++)
                    Cf[(size_t)(m_base + r) * N + n_g] = acc[mf][nf][r];
            }
    }
}

// ---------------- causal flash attention (v7: KVBLK=128, balanced pairs) -----
// grid (NH, 16); 512 thr = 8 waves; QBLK=128. Block (h, by) processes strips
// {by, 31-by} sequentially -> exactly 33 KV-tiles (KVBLK=128) per block: all
// 256 blocks identical, 1/CU, zero tail. 128 KB LDS (dbuf K[128x128] +
// VT[128x128]). Swapped math (S^T = mfma(K,Q)), in-lane softmax, in-register
// P (cvt_pk + shfl), T13 defer-max, LDS-scratch epilogue.
__global__ __launch_bounds__(512) void attn(
    const unsigned short* __restrict__ Q, const unsigned short* __restrict__ Kc,
    const unsigned short* __restrict__ VT, unsigned short* __restrict__ O) {
    __shared__ __align__(16) unsigned short SMEM[65536];   // 128 KB
    unsigned short* KB = SMEM;              // [2][128*128]
    unsigned short* VB = SMEM + 32768;      // [2][128*128]
    int h = blockIdx.x;
    int by = blockIdx.y;
    int t = threadIdx.x, lane = t & 63, w = t >> 6;
    int lr = lane & 15, hi = lane >> 4;
    const float scale = 0.08838834764831845f;  // 1/sqrt(128)

    auto stage = [&](int buf, int kv0) {
#pragma unroll
        for (int i = 0; i < 4; i++) {
            int idx = i * 512 + t;            // 0..2047
            int r = idx >> 4, s = idx & 15;   // K: 128 rows x 16 slots
            gl2lds16(Kc + (size_t)(kv0 + r) * HID + h * HD + ((s ^ (r & 7)) << 3),
                     (void*)(KB + buf * 16384 + ((i * 512 + w * 64) << 3)));
        }
#pragma unroll
        for (int i = 0; i < 4; i++) {
            int idx = i * 512 + t;
            int r = idx >> 4, s = idx & 15;   // VT: 128 rows x 16 slots
            gl2lds16(VT + (size_t)(h * HD + r) * SQ + kv0 + ((s ^ (r & 7)) << 3),
                     (void*)(VB + buf * 16384 + ((i * 512 + w * 64) << 3)));
        }
    };

    int strips[2] = {31 - by, by};
    for (int sp = 0; sp < 2; sp++) {
        int strip = strips[sp];
        int qbase = strip * 128;
        int wq0 = qbase + w * 16;
        int qg = wq0 + lr;                 // this lane's q row

        stage(0, 0);
        bf16x8 qf[4];
        for (int ks = 0; ks < 4; ks++)
            qf[ks] = *(const bf16x8*)(Q + (size_t)qg * HID + h * HD + ks * 32 + (hi << 3));
        f32x4 o_acc[8] = {};               // O^T frags: d=16c2+4hi+reg, q=lane&15
        float m_r = -1e30f, l_r = 0.f;
        __syncthreads();

        int nt = strip + 1;                // 128-wide KV tiles for this strip
        int cur = 0;
        for (int tile = 0; tile < nt; tile++) {
            int kv0 = tile * 128;
            if (tile + 1 < nt) stage(cur ^ 1, kv0 + 128);   // async prefetch
            const unsigned short* Kl = KB + cur * 16384;
            const unsigned short* Vl = VB + cur * 16384;

            if (kv0 <= wq0 + 15) {   // not fully above this wave's diagonal
                // S^T = mfma(K, Q): sfr[c][r] = S^T[k=16c+4hi+r][q=lane&15]
                f32x4 sfr[8];
#pragma unroll
                for (int c = 0; c < 8; c++) {
                    f32x4 s = {0.f, 0.f, 0.f, 0.f};
#pragma unroll
                    for (int ks = 0; ks < 4; ks++) {
                        bf16x8 kf = *(const bf16x8*)(Kl + (c * 16 + lr) * 128 +
                                                     (((ks * 4 + hi) ^ (lr & 7)) << 3));
                        s = __builtin_amdgcn_mfma_f32_16x16x32_bf16(kf, qf[ks], s, 0, 0, 0);
                    }
                    sfr[c] = s;
                }
                // scale + causal mask (k_g <= q_g)
                if (kv0 + 127 > wq0) {
#pragma unroll
                    for (int c = 0; c < 8; c++) {
                        int kgb = kv0 + c * 16 + 4 * hi;
                        for (int r = 0; r < 4; r++) {
                            float v = sfr[c][r] * scale;
                            sfr[c][r] = (kgb + r <= qg) ? v : -1e30f;
                        }
                    }
                } else {
#pragma unroll
                    for (int c = 0; c < 8; c++)
                        for (int r = 0; r < 4; r++) sfr[c][r] *= scale;
                }
                // in-lane row max (32 values) + cross-hi (2 shfl_xor)
                float mx = -1e30f;
#pragma unroll
                for (int c = 0; c < 8; c++)
                    mx = fmaxf(mx, fmaxf(fmaxf(sfr[c][0], sfr[c][1]),
                                         fmaxf(sfr[c][2], sfr[c][3])));
                mx = fmaxf(mx, __shfl_xor(mx, 16));
                mx = fmaxf(mx, __shfl_xor(mx, 32));
                // T13 defer-max
                if (__all((mx - m_r) <= 8.0f)) {
                    float rs = 0.f;
#pragma unroll
                    for (int c = 0; c < 8; c++)
                        for (int r = 0; r < 4; r++) {
                            float p = __expf(sfr[c][r] - m_r);
                            sfr[c][r] = p;
                            rs += p;
                        }
                    rs += __shfl_xor(rs, 16);
                    rs += __shfl_xor(rs, 32);
                    l_r += rs;
                } else {
                    float mn = fmaxf(m_r, mx);
                    float alpha = __expf(m_r - mn);
                    m_r = mn;
                    float rs = 0.f;
#pragma unroll
                    for (int c = 0; c < 8; c++)
                        for (int r = 0; r < 4; r++) {
                            float p = __expf(sfr[c][r] - mn);
                            sfr[c][r] = p;
                            rs += p;
                        }
                    rs += __shfl_xor(rs, 16);
                    rs += __shfl_xor(rs, 32);
                    l_r = l_r * alpha + rs;
                    for (int c2 = 0; c2 < 8; c2++)
                        for (int r = 0; r < 4; r++) o_acc[c2][r] *= alpha;
                }

                // P^T -> PV B-operand fragments, fully in-register.
                unsigned int wpk[8][2];
#pragma unroll
                for (int c = 0; c < 8; c++)
#pragma unroll
                    for (int i = 0; i < 2; i++) {
                        unsigned int d;
                        asm("v_cvt_pk_bf16_f32 %0, %1, %2"
                            : "=v"(d) : "v"(sfr[c][2 * i]), "v"(sfr[c][2 * i + 1]));
                        wpk[c][i] = d;
                    }
                int srcA = lr + ((hi & 1) << 5);
                int srcB = srcA + 16;
                bool sel = (hi & 2);
#pragma unroll
                for (int kk = 0; kk < 4; kk++) {
                    unsigned int a0 = __shfl(wpk[2 * kk][0], srcA);
                    unsigned int a1 = __shfl(wpk[2 * kk][1], srcA);
                    unsigned int a2 = __shfl(wpk[2 * kk][0], srcB);
                    unsigned int a3 = __shfl(wpk[2 * kk][1], srcB);
                    unsigned int b0 = __shfl(wpk[2 * kk + 1][0], srcA);
                    unsigned int b1 = __shfl(wpk[2 * kk + 1][1], srcA);
                    unsigned int b2 = __shfl(wpk[2 * kk + 1][0], srcB);
                    unsigned int b3 = __shfl(wpk[2 * kk + 1][1], srcB);
                    union { unsigned int u[4]; bf16x8 v; } pf;
                    pf.u[0] = sel ? b0 : a0;
                    pf.u[1] = sel ? b1 : a1;
                    pf.u[2] = sel ? b2 : a2;
                    pf.u[3] = sel ? b3 : a3;
                    // O^T += V^T @ P^T : A = V^T (rows d), B = P^T frag
#pragma unroll
                    for (int c2 = 0; c2 < 8; c2++) {
                        bf16x8 vv = *(const bf16x8*)(Vl + (c2 * 16 + lr) * 128 +
                                                     (((kk * 4 + hi) ^ (lr & 7)) << 3));
                        o_acc[c2] = __builtin_amdgcn_mfma_f32_16x16x32_bf16(
                            vv, pf.v, o_acc[c2], 0, 0, 0);
                    }
                }
            }
            __syncthreads();   // drains prefetch vmcnt + syncs buffer flip
            cur ^= 1;
        }

        // epilogue: O^T -> O via per-wave bf16 LDS scratch (within-wave only).
        unsigned short* scr = SMEM + w * 2176;   // 16 rows x 136 bf16
        float invl = 1.0f / l_r;
        for (int c2 = 0; c2 < 8; c2++) {
            us4 o;
            o.x = f2bf(o_acc[c2][0] * invl); o.y = f2bf(o_acc[c2][1] * invl);
            o.z = f2bf(o_acc[c2][2] * invl); o.w = f2bf(o_acc[c2][3] * invl);
            *(us4*)(scr + lr * 136 + c2 * 16 + hi * 4) = o;
        }
        for (int j = 0; j < 4; j++) {
            bf16x8 v = *(const bf16x8*)(scr + lr * 136 + hi * 32 + j * 8);
            *(bf16x8*)(O + (size_t)qg * HID + h * HD + hi * 32 + j * 8) = v;
        }
        __syncthreads();   // scratch reads done before next strip re-stages
    }
}

// ---------------------------------------------------------------------------
extern "C" void kernel_launch(void* const* d_in, const int* in_sizes, int n_in,
                              void* d_out, int out_size, void* d_ws, size_t ws_size,
                              hipStream_t stream) {
    const float* x  = (const float*)d_in[0];
    const float* Wq = (const float*)d_in[1];
    const float* bq = (const float*)d_in[2];
    const float* Wk = (const float*)d_in[3];
    const float* bk = (const float*)d_in[4];
    const float* Wv = (const float*)d_in[5];
    const float* bv = (const float*)d_in[6];
    const float* Wo = (const float*)d_in[7];

    char* ws = (char*)d_ws;
    const size_t MB = 1024 * 1024;
    unsigned short* xb    = (unsigned short*)(ws + 0 * MB);
    unsigned short* WTall = (unsigned short*)(ws + 16 * MB);   // 4 x 8 MB
    unsigned short* Qb    = (unsigned short*)(ws + 48 * MB);
    unsigned short* Kbuf  = (unsigned short*)(ws + 64 * MB);
    unsigned short* VTb   = (unsigned short*)(ws + 80 * MB);
    unsigned short* Ctx   = (unsigned short*)(ws + 96 * MB);

    // 1. x -> bf16
    cvt_f32_bf16<<<8192, 256, 0, stream>>>(x, xb, SQ * HID);
    // 2. all 4 weights -> transposed bf16 (one dispatch)
    transcvt4<<<dim3(HID / 64, HID / 64, 4), 256, 0, stream>>>(Wq, Wk, Wv, Wo, WTall);
    // 3. fused QKV projections (1536 blocks, 2 blocks/CU resident)
    gemm_pipe<0><<<dim3(32, 48), 256, 0, stream>>>(xb, WTall, bq, bk, bv,
                                                   Qb, Kbuf, VTb, nullptr);
    // 4. causal attention (256 identical blocks, 1/CU)
    attn<<<dim3(NH, 16), 512, 0, stream>>>(Qb, Kbuf, VTb, Ctx);
    // 5. output projection (512 blocks, 2 blocks/CU resident)
    gemm_pipe<1><<<dim3(32, 16), 256, 0, stream>>>(Ctx, WTall, nullptr, nullptr,
                                                   nullptr, nullptr, nullptr,
                                                   nullptr, (float*)d_out);
}